// Round 1
// baseline (1676.223 us; speedup 1.0000x reference)
//
#include <hip/hip_runtime.h>
#include <cstdint>
#include <cstddef>

#define N_TOT   53248
#define N_HOPS  4096
#define HOP_LEN 12
#define DIMH    256
#define NHEAD   8
#define FFD     1024
#define CHUNK   4096   // FFN row chunk (13 chunks)

// ---------------------------------------------------------------------------
// prep: wsrc[d][h] = sum_c W[d][h*256+c]*att_src[h][c]
//       wdst likewise; Wm[d][c] = (1/8) sum_h W[d][h*256+c];
//       B2[(h*256+d)][c] = W[d][h*256+c]   (permuted W for hop GEMM)
// grid = 256 (d), block = 256 (c)
// ---------------------------------------------------------------------------
__global__ __launch_bounds__(256) void prep_w(
    const float* __restrict__ W, const float* __restrict__ att_s,
    const float* __restrict__ att_d, float* __restrict__ wsrc,
    float* __restrict__ wdst, float* __restrict__ Wm, float* __restrict__ B2)
{
    int d = blockIdx.x, c = threadIdx.x;
    __shared__ float red[256];
    float wm = 0.f;
    for (int h = 0; h < NHEAD; ++h) {
        float w = W[d * 2048 + h * 256 + c];
        wm += w;
        B2[(size_t)(h * 256 + d) * 256 + c] = w;

        red[c] = w * att_s[h * 256 + c];
        __syncthreads();
        for (int s = 128; s > 0; s >>= 1) { if (c < s) red[c] += red[c + s]; __syncthreads(); }
        if (c == 0) wsrc[d * 8 + h] = red[0];
        __syncthreads();

        red[c] = w * att_d[h * 256 + c];
        __syncthreads();
        for (int s = 128; s > 0; s >>= 1) { if (c < s) red[c] += red[c + s]; __syncthreads(); }
        if (c == 0) wdst[d * 8 + h] = red[0];
        __syncthreads();
    }
    Wm[d * 256 + c] = wm * 0.125f;
}

// ---------------------------------------------------------------------------
// a_s[n][h] = x[n,:] @ wsrc[:,h]; a_d likewise. One wave per node.
// block = 256 (4 waves), grid = N/4
// ---------------------------------------------------------------------------
__global__ __launch_bounds__(256) void a_proj(
    const float* __restrict__ x, const float* __restrict__ wsrc,
    const float* __restrict__ wdst, float* __restrict__ a_s, float* __restrict__ a_d)
{
    __shared__ float sws[NHEAD * 256], swd[NHEAD * 256];  // transposed: [h][d]
    int tid = threadIdx.x;
    for (int i = tid; i < 2048; i += 256) {
        int d = i >> 3, h = i & 7;
        sws[h * 256 + d] = wsrc[i];
        swd[h * 256 + d] = wdst[i];
    }
    __syncthreads();
    int wave = tid >> 6, lane = tid & 63;
    int n = blockIdx.x * 4 + wave;
    float xs[4];
    for (int i = 0; i < 4; ++i) xs[i] = x[(size_t)n * 256 + i * 64 + lane];
    for (int h = 0; h < NHEAD; ++h) {
        float acc = 0.f;
        for (int i = 0; i < 4; ++i) acc += xs[i] * sws[h * 256 + i * 64 + lane];
        for (int o = 32; o > 0; o >>= 1) acc += __shfl_down(acc, o);
        if (lane == 0) a_s[n * 8 + h] = acc;
        acc = 0.f;
        for (int i = 0; i < 4; ++i) acc += xs[i] * swd[h * 256 + i * 64 + lane];
        for (int o = 32; o > 0; o >>= 1) acc += __shfl_down(acc, o);
        if (lane == 0) a_d[n * 8 + h] = acc;
    }
}

// ---------------------------------------------------------------------------
// hop softmax + weighted x aggregation:
// z[j][h][d] = sum_e alpha[e,h]/8 * x[src_e][d], edges = {self x2, 12 members}
// grid = 4096 (j), block = 256 (d)
// ---------------------------------------------------------------------------
__global__ __launch_bounds__(256) void hop_z(
    const float* __restrict__ x, const float* __restrict__ a_s,
    const float* __restrict__ a_d, float* __restrict__ z)
{
    int j = blockIdx.x, tid = threadIdx.x;
    __shared__ float xr[13][256];
    __shared__ float alpha[NHEAD][13];
    for (int r = 0; r < 13; ++r) {
        int src = (r == 0) ? j : (N_HOPS + j * HOP_LEN + (r - 1));
        xr[r][tid] = x[(size_t)src * 256 + tid];
    }
    if (tid < NHEAD) {
        int h = tid;
        float ad = a_d[j * 8 + h];
        float e[13];
        float v = a_s[j * 8 + h] + ad; v = v > 0.f ? v : 0.2f * v;
        e[0] = v; float mx = v;
        for (int k = 0; k < HOP_LEN; ++k) {
            int src = N_HOPS + j * HOP_LEN + k;
            float u = a_s[src * 8 + h] + ad; u = u > 0.f ? u : 0.2f * u;
            e[k + 1] = u; mx = fmaxf(mx, u);
        }
        // self edge appears TWICE (edge_index self + auto self-loop)
        float sum = 2.f * expf(e[0] - mx);
        for (int k = 1; k < 13; ++k) sum += expf(e[k] - mx);
        float inv = 0.125f / (sum + 1e-16f);   // fold mean-over-heads
        alpha[h][0] = 2.f * expf(e[0] - mx) * inv;
        for (int k = 1; k < 13; ++k) alpha[h][k] = expf(e[k] - mx) * inv;
    }
    __syncthreads();
    for (int h = 0; h < NHEAD; ++h) {
        float acc = 0.f;
        for (int r = 0; r < 13; ++r) acc += alpha[h][r] * xr[r][tid];
        z[((size_t)j * NHEAD + h) * 256 + tid] = acc;
    }
}

// ---------------------------------------------------------------------------
// fp32 tiled GEMM: C[M,Nc] = A[M,K] @ B[K,Nc] (+bias) (opt relu)
// BM=BN=64, BK=16, 256 threads, 4x4 per thread
// ---------------------------------------------------------------------------
template <int RELU>
__global__ __launch_bounds__(256) void gemm_f32(
    const float* __restrict__ A, const float* __restrict__ B,
    const float* __restrict__ bias, float* __restrict__ Cm,
    int M, int Nc, int K)
{
    __shared__ float As[16][65];   // [k][m], +1 pad to break write conflicts
    __shared__ float Bs[16][64];   // [k][n]
    int tid = threadIdx.x;
    int bm = blockIdx.y * 64, bn = blockIdx.x * 64;
    int ar = tid >> 2, ac4 = (tid & 3) * 4;     // A tile load: row ar, 4 cols
    int br = tid >> 4, bc4 = (tid & 15) * 4;    // B tile load: row br, 4 cols
    int tm = (tid >> 4) * 4, tn = (tid & 15) * 4;
    float acc[4][4] = {};
    for (int k0 = 0; k0 < K; k0 += 16) {
        float4 av = *(const float4*)(A + (size_t)(bm + ar) * K + k0 + ac4);
        float4 bv = *(const float4*)(B + (size_t)(k0 + br) * Nc + bn + bc4);
        As[ac4 + 0][ar] = av.x; As[ac4 + 1][ar] = av.y;
        As[ac4 + 2][ar] = av.z; As[ac4 + 3][ar] = av.w;
        *(float4*)&Bs[br][bc4] = bv;
        __syncthreads();
        #pragma unroll
        for (int kk = 0; kk < 16; ++kk) {
            float a0 = As[kk][tm], a1 = As[kk][tm + 1], a2 = As[kk][tm + 2], a3 = As[kk][tm + 3];
            float b0 = Bs[kk][tn], b1 = Bs[kk][tn + 1], b2 = Bs[kk][tn + 2], b3 = Bs[kk][tn + 3];
            acc[0][0] += a0 * b0; acc[0][1] += a0 * b1; acc[0][2] += a0 * b2; acc[0][3] += a0 * b3;
            acc[1][0] += a1 * b0; acc[1][1] += a1 * b1; acc[1][2] += a1 * b2; acc[1][3] += a1 * b3;
            acc[2][0] += a2 * b0; acc[2][1] += a2 * b1; acc[2][2] += a2 * b2; acc[2][3] += a2 * b3;
            acc[3][0] += a3 * b0; acc[3][1] += a3 * b1; acc[3][2] += a3 * b2; acc[3][3] += a3 * b3;
        }
        __syncthreads();
    }
    #pragma unroll
    for (int i = 0; i < 4; ++i) {
        #pragma unroll
        for (int jj = 0; jj < 4; ++jj) {
            float v = acc[i][jj];
            if (bias) v += bias[bn + tn + jj];
            if (RELU) v = fmaxf(v, 0.f);
            Cm[(size_t)(bm + tm + i) * Nc + bn + tn + jj] = v;
        }
    }
}

// ---------------------------------------------------------------------------
// out = LayerNorm(a + b) * g + be ; one wave per row (256 dims)
// ---------------------------------------------------------------------------
__global__ __launch_bounds__(256) void ln_add(
    const float* __restrict__ a, const float* __restrict__ b,
    const float* __restrict__ g, const float* __restrict__ be,
    float* __restrict__ out)
{
    int wave = threadIdx.x >> 6, lane = threadIdx.x & 63;
    int n = blockIdx.x * 4 + wave;
    float v[4];
    float s = 0.f;
    for (int i = 0; i < 4; ++i) {
        size_t idx = (size_t)n * 256 + i * 64 + lane;
        v[i] = a[idx] + b[idx];
        s += v[i];
    }
    for (int o = 32; o > 0; o >>= 1) s += __shfl_xor(s, o);
    float mu = s * (1.f / 256.f);
    float q = 0.f;
    for (int i = 0; i < 4; ++i) { float d = v[i] - mu; q += d * d; }
    for (int o = 32; o > 0; o >>= 1) q += __shfl_xor(q, o);
    float rstd = rsqrtf(q * (1.f / 256.f) + 1e-5f);
    for (int i = 0; i < 4; ++i) {
        int c = i * 64 + lane;
        out[(size_t)n * 256 + c] = (v[i] - mu) * rstd * g[c] + be[c];
    }
}

// ---------------------------------------------------------------------------
extern "C" void kernel_launch(void* const* d_in, const int* in_sizes, int n_in,
                              void* d_out, int out_size, void* d_ws, size_t ws_size,
                              hipStream_t stream)
{
    const float* x       = (const float*)d_in[0];
    // d_in[1] = edge_index (structure is fixed; hardcoded)
    const float* gat_W   = (const float*)d_in[2];
    const float* att_src = (const float*)d_in[3];
    const float* att_dst = (const float*)d_in[4];
    const float* gat_b   = (const float*)d_in[5];
    const float* W1      = (const float*)d_in[6];
    const float* b1      = (const float*)d_in[7];
    const float* W2      = (const float*)d_in[8];
    const float* b2      = (const float*)d_in[9];
    const float* ln1_g   = (const float*)d_in[10];
    const float* ln1_b   = (const float*)d_in[11];
    const float* ln2_g   = (const float*)d_in[12];
    const float* ln2_b   = (const float*)d_in[13];
    float* out = (float*)d_out;

    // workspace layout (floats)
    float* ws   = (float*)d_ws;
    float* x1   = ws;                                   // N*256
    float* gbuf = x1 + (size_t)N_TOT * 256;             // N*256 (g_out, later ff)
    float* zbuf = gbuf + (size_t)N_TOT * 256;           // 4096*2048 (z, later hidden)
    float* a_s  = zbuf + (size_t)N_HOPS * 2048;         // N*8
    float* a_d  = a_s + (size_t)N_TOT * 8;              // N*8
    float* wsrc = a_d + (size_t)N_TOT * 8;              // 256*8
    float* wdst = wsrc + 256 * 8;                       // 256*8
    float* Wm   = wdst + 256 * 8;                       // 256*256
    float* B2   = Wm + 256 * 256;                       // 2048*256

    // 1. weight prep
    hipLaunchKernelGGL(prep_w, dim3(256), dim3(256), 0, stream,
                       gat_W, att_src, att_dst, wsrc, wdst, Wm, B2);
    // 2. attention logit projections
    hipLaunchKernelGGL(a_proj, dim3(N_TOT / 4), dim3(256), 0, stream,
                       x, wsrc, wdst, a_s, a_d);
    // 3. hop softmax + weighted x aggregation
    hipLaunchKernelGGL(hop_z, dim3(N_HOPS), dim3(256), 0, stream,
                       x, a_s, a_d, zbuf);
    // 4. g_all = x @ Wm + bias (all nodes; hop rows overwritten next)
    hipLaunchKernelGGL((gemm_f32<0>), dim3(256 / 64, N_TOT / 64), dim3(256), 0, stream,
                       x, Wm, gat_b, gbuf, N_TOT, 256, 256);
    // 5. g_hop = z @ B2 + bias (overwrites rows 0..4095)
    hipLaunchKernelGGL((gemm_f32<0>), dim3(256 / 64, N_HOPS / 64), dim3(256), 0, stream,
                       zbuf, B2, gat_b, gbuf, N_HOPS, 256, 2048);
    // 6. x1 = LN(g + x)
    hipLaunchKernelGGL(ln_add, dim3(N_TOT / 4), dim3(256), 0, stream,
                       gbuf, x, ln1_g, ln1_b, x1);
    // 7. FFN in row chunks; hidden reuses zbuf, ff reuses gbuf
    for (int c0 = 0; c0 < N_TOT; c0 += CHUNK) {
        hipLaunchKernelGGL((gemm_f32<1>), dim3(FFD / 64, CHUNK / 64), dim3(256), 0, stream,
                           x1 + (size_t)c0 * 256, W1, b1, zbuf, CHUNK, FFD, 256);
        hipLaunchKernelGGL((gemm_f32<0>), dim3(256 / 64, CHUNK / 64), dim3(256), 0, stream,
                           zbuf, W2, b2, gbuf + (size_t)c0 * 256, CHUNK, 256, FFD);
    }
    // 8. out = LN(ff + x1)
    hipLaunchKernelGGL(ln_add, dim3(N_TOT / 4), dim3(256), 0, stream,
                       gbuf, x1, ln2_g, ln2_b, out);
    (void)in_sizes; (void)n_in; (void)out_size; (void)ws_size;
}

// Round 2
// 514.457 us; speedup vs baseline: 3.2582x; 3.2582x over previous
//
#include <hip/hip_runtime.h>
#include <cstdint>
#include <cstddef>

#define N_TOT   53248
#define N_HOPS  4096
#define HOP_LEN 12
#define NHEAD   8
#define FFD     1024
#define CHUNK   8192

typedef __bf16 bf16x8 __attribute__((ext_vector_type(8)));
typedef float f32x4 __attribute__((ext_vector_type(4)));

__device__ __forceinline__ unsigned short f2bf(float f) {
    unsigned int u = __float_as_uint(f);
    u += 0x7FFFu + ((u >> 16) & 1u);
    return (unsigned short)(u >> 16);
}
__device__ __forceinline__ float bf2f(unsigned short b) {
    return __uint_as_float((unsigned int)b << 16);
}
__device__ __forceinline__ void gload16(const void* g, void* l) {
    __builtin_amdgcn_global_load_lds(
        (const __attribute__((address_space(1))) void*)g,
        (__attribute__((address_space(3))) void*)l, 16, 0, 0);
}

// ---------------------------------------------------------------------------
// prep: wsrc[d][h] = sum_c W[d][h*256+c]*att_src[h][c]; wdst likewise;
//       WmT[c][d] = bf16( (1/8) sum_h W[d][h*256+c] )   (transposed, N x K)
// grid = 256 (d), block = 256 (c)
// ---------------------------------------------------------------------------
__global__ __launch_bounds__(256) void prep_w(
    const float* __restrict__ W, const float* __restrict__ att_s,
    const float* __restrict__ att_d, float* __restrict__ wsrc,
    float* __restrict__ wdst, unsigned short* __restrict__ WmT)
{
    int d = blockIdx.x, c = threadIdx.x;
    __shared__ float red[256];
    float wm = 0.f;
    for (int h = 0; h < NHEAD; ++h) {
        float w = W[d * 2048 + h * 256 + c];
        wm += w;
        red[c] = w * att_s[h * 256 + c];
        __syncthreads();
        for (int s = 128; s > 0; s >>= 1) { if (c < s) red[c] += red[c + s]; __syncthreads(); }
        if (c == 0) wsrc[d * 8 + h] = red[0];
        __syncthreads();
        red[c] = w * att_d[h * 256 + c];
        __syncthreads();
        for (int s = 128; s > 0; s >>= 1) { if (c < s) red[c] += red[c + s]; __syncthreads(); }
        if (c == 0) wdst[d * 8 + h] = red[0];
        __syncthreads();
    }
    WmT[c * 256 + d] = f2bf(wm * 0.125f);
}

// ---------------------------------------------------------------------------
// tiled transpose + f32->bf16: out[c*OS + r] = bf16(in[r*IS + c])
// block (32,8); grid (C/32, R/32, nz); per-z: in += z*in_zoff, out += z*out_zoff
// ---------------------------------------------------------------------------
__global__ __launch_bounds__(256) void tconv(
    const float* __restrict__ in, unsigned short* __restrict__ out,
    int IS, int OS, int in_zoff, int out_zoff)
{
    __shared__ float t[32][33];
    in  += (size_t)blockIdx.z * in_zoff;
    out += (size_t)blockIdx.z * out_zoff;
    int tx = threadIdx.x, ty = threadIdx.y;
    int c0 = blockIdx.x * 32, r0 = blockIdx.y * 32;
    #pragma unroll
    for (int k = 0; k < 4; ++k)
        t[ty + 8 * k][tx] = in[(size_t)(r0 + ty + 8 * k) * IS + c0 + tx];
    __syncthreads();
    #pragma unroll
    for (int k = 0; k < 4; ++k)
        out[(size_t)(c0 + ty + 8 * k) * OS + r0 + tx] = f2bf(t[tx][ty + 8 * k]);
}

// ---------------------------------------------------------------------------
__global__ __launch_bounds__(256) void cvt_bf16(
    const float* __restrict__ in, unsigned short* __restrict__ out, int n4)
{
    int i = blockIdx.x * 256 + threadIdx.x;
    if (i >= n4) return;
    float4 v = ((const float4*)in)[i];
    ushort4 o;
    o.x = f2bf(v.x); o.y = f2bf(v.y); o.z = f2bf(v.z); o.w = f2bf(v.w);
    ((ushort4*)out)[i] = o;
}

// ---------------------------------------------------------------------------
// a_s[n][h] = x[n,:] @ wsrc[:,h]; a_d likewise. One wave per node.
// ---------------------------------------------------------------------------
__global__ __launch_bounds__(256) void a_proj(
    const float* __restrict__ x, const float* __restrict__ wsrc,
    const float* __restrict__ wdst, float* __restrict__ a_s, float* __restrict__ a_d)
{
    __shared__ float sws[NHEAD * 256], swd[NHEAD * 256];  // [h][d]
    int tid = threadIdx.x;
    for (int i = tid; i < 2048; i += 256) {
        int d = i >> 3, h = i & 7;
        sws[h * 256 + d] = wsrc[i];
        swd[h * 256 + d] = wdst[i];
    }
    __syncthreads();
    int wave = tid >> 6, lane = tid & 63;
    int n = blockIdx.x * 4 + wave;
    float xs[4];
    for (int i = 0; i < 4; ++i) xs[i] = x[(size_t)n * 256 + i * 64 + lane];
    for (int h = 0; h < NHEAD; ++h) {
        float acc = 0.f;
        for (int i = 0; i < 4; ++i) acc += xs[i] * sws[h * 256 + i * 64 + lane];
        for (int o = 32; o > 0; o >>= 1) acc += __shfl_down(acc, o);
        if (lane == 0) a_s[n * 8 + h] = acc;
        acc = 0.f;
        for (int i = 0; i < 4; ++i) acc += xs[i] * swd[h * 256 + i * 64 + lane];
        for (int o = 32; o > 0; o >>= 1) acc += __shfl_down(acc, o);
        if (lane == 0) a_d[n * 8 + h] = acc;
    }
}

// ---------------------------------------------------------------------------
// hop softmax + weighted x aggregation (bf16 output):
// z[j][h*256+d] = bf16( sum_e alpha[e,h]/8 * x[src_e][d] )
// ---------------------------------------------------------------------------
__global__ __launch_bounds__(256) void hop_z(
    const float* __restrict__ x, const float* __restrict__ a_s,
    const float* __restrict__ a_d, unsigned short* __restrict__ z)
{
    int j = blockIdx.x, tid = threadIdx.x;
    __shared__ float xr[13][256];
    __shared__ float alpha[NHEAD][13];
    for (int r = 0; r < 13; ++r) {
        int src = (r == 0) ? j : (N_HOPS + j * HOP_LEN + (r - 1));
        xr[r][tid] = x[(size_t)src * 256 + tid];
    }
    if (tid < NHEAD) {
        int h = tid;
        float ad = a_d[j * 8 + h];
        float e[13];
        float v = a_s[j * 8 + h] + ad; v = v > 0.f ? v : 0.2f * v;
        e[0] = v; float mx = v;
        for (int k = 0; k < HOP_LEN; ++k) {
            int src = N_HOPS + j * HOP_LEN + k;
            float u = a_s[src * 8 + h] + ad; u = u > 0.f ? u : 0.2f * u;
            e[k + 1] = u; mx = fmaxf(mx, u);
        }
        float sum = 2.f * expf(e[0] - mx);   // self edge counted twice
        for (int k = 1; k < 13; ++k) sum += expf(e[k] - mx);
        float inv = 0.125f / (sum + 1e-16f);
        alpha[h][0] = 2.f * expf(e[0] - mx) * inv;
        for (int k = 1; k < 13; ++k) alpha[h][k] = expf(e[k] - mx) * inv;
    }
    __syncthreads();
    for (int h = 0; h < NHEAD; ++h) {
        float acc = 0.f;
        for (int r = 0; r < 13; ++r) acc += alpha[h][r] * xr[r][tid];
        z[((size_t)j * NHEAD + h) * 256 + tid] = f2bf(acc);
    }
}

// ---------------------------------------------------------------------------
// bf16 MFMA GEMM: C[M,Nc] = A[M,K](bf16) @ BT[Nc,K](bf16)^T + bias
// 128x128 tile, BK=32, 256 threads (4 waves, 2x2), 64x64 per wave,
// global_load_lds 16B staging (m97 structure). M%128==0, Nc%128==0, K%32==0.
// ---------------------------------------------------------------------------
template <int RELU, int OUT_BF16>
__global__ __launch_bounds__(256) void gemm_bt(
    const unsigned short* __restrict__ A, const unsigned short* __restrict__ BT,
    const float* __restrict__ bias, void* __restrict__ Cout,
    int M, int Nc, int K)
{
    __shared__ __align__(16) unsigned short As[128 * 32];
    __shared__ __align__(16) unsigned short Bs[128 * 32];
    const int tid = threadIdx.x;
    const int l = tid & 63;
    const int bm = blockIdx.y * 128, bn = blockIdx.x * 128;
    const int wm = ((tid >> 6) >> 1) * 64, wn = ((tid >> 6) & 1) * 64;

    // staging: chunk c in [0,512): LDS byte off = c*16, row = c>>2, k-elem = (c&3)*8
    const int r0 = tid >> 2, ke0 = (tid & 3) * 8;
    const int r1 = (256 + tid) >> 2, ke1 = ((256 + tid) & 3) * 8;
    const unsigned short* ga0 = A + (size_t)(bm + r0) * K + ke0;
    const unsigned short* ga1 = A + (size_t)(bm + r1) * K + ke1;
    const unsigned short* gb0 = BT + (size_t)(bn + r0) * K + ke0;
    const unsigned short* gb1 = BT + (size_t)(bn + r1) * K + ke1;

    f32x4 acc[4][4];
    #pragma unroll
    for (int m = 0; m < 4; ++m)
        #pragma unroll
        for (int n = 0; n < 4; ++n)
            acc[m][n] = (f32x4){0.f, 0.f, 0.f, 0.f};

    const int lrow = l & 15, lk8 = (l >> 4) * 8;

    for (int k0 = 0; k0 < K; k0 += 32) {
        gload16(ga0 + k0, &As[(size_t)tid * 8]);
        gload16(ga1 + k0, &As[(size_t)(256 + tid) * 8]);
        gload16(gb0 + k0, &Bs[(size_t)tid * 8]);
        gload16(gb1 + k0, &Bs[(size_t)(256 + tid) * 8]);
        __syncthreads();
        bf16x8 af[4], bfr[4];
        #pragma unroll
        for (int m = 0; m < 4; ++m)
            af[m] = *(const bf16x8*)&As[(wm + m * 16 + lrow) * 32 + lk8];
        #pragma unroll
        for (int n = 0; n < 4; ++n)
            bfr[n] = *(const bf16x8*)&Bs[(wn + n * 16 + lrow) * 32 + lk8];
        #pragma unroll
        for (int m = 0; m < 4; ++m)
            #pragma unroll
            for (int n = 0; n < 4; ++n)
                acc[m][n] = __builtin_amdgcn_mfma_f32_16x16x32_bf16(
                    af[m], bfr[n], acc[m][n], 0, 0, 0);
        __syncthreads();
    }

    const int orow = (l >> 4) * 4, ocol = l & 15;
    #pragma unroll
    for (int m = 0; m < 4; ++m) {
        int gr = bm + wm + m * 16 + orow;
        #pragma unroll
        for (int n = 0; n < 4; ++n) {
            int gc = bn + wn + n * 16 + ocol;
            float bv = bias[gc];
            #pragma unroll
            for (int r = 0; r < 4; ++r) {
                float v = acc[m][n][r] + bv;
                if (RELU) v = fmaxf(v, 0.f);
                if (OUT_BF16)
                    ((unsigned short*)Cout)[(size_t)(gr + r) * Nc + gc] = f2bf(v);
                else
                    ((float*)Cout)[(size_t)(gr + r) * Nc + gc] = v;
            }
        }
    }
}

// ---------------------------------------------------------------------------
// out = LayerNorm(a + b) * g + be ; one wave per 256-dim row
// ---------------------------------------------------------------------------
template <int B_BF16, int OUT_BF16>
__global__ __launch_bounds__(256) void ln_add(
    const float* __restrict__ a, const void* __restrict__ bv,
    const float* __restrict__ g, const float* __restrict__ be,
    void* __restrict__ outv)
{
    int wave = threadIdx.x >> 6, lane = threadIdx.x & 63;
    int n = blockIdx.x * 4 + wave;
    float v[4];
    float s = 0.f;
    for (int i = 0; i < 4; ++i) {
        size_t idx = (size_t)n * 256 + i * 64 + lane;
        float b = B_BF16 ? bf2f(((const unsigned short*)bv)[idx])
                         : ((const float*)bv)[idx];
        v[i] = a[idx] + b;
        s += v[i];
    }
    for (int o = 32; o > 0; o >>= 1) s += __shfl_xor(s, o);
    float mu = s * (1.f / 256.f);
    float q = 0.f;
    for (int i = 0; i < 4; ++i) { float d = v[i] - mu; q += d * d; }
    for (int o = 32; o > 0; o >>= 1) q += __shfl_xor(q, o);
    float rstd = rsqrtf(q * (1.f / 256.f) + 1e-5f);
    for (int i = 0; i < 4; ++i) {
        int c = i * 64 + lane;
        float r = (v[i] - mu) * rstd * g[c] + be[c];
        size_t idx = (size_t)n * 256 + c;
        if (OUT_BF16) ((unsigned short*)outv)[idx] = f2bf(r);
        else          ((float*)outv)[idx] = r;
    }
}

// ---------------------------------------------------------------------------
extern "C" void kernel_launch(void* const* d_in, const int* in_sizes, int n_in,
                              void* d_out, int out_size, void* d_ws, size_t ws_size,
                              hipStream_t stream)
{
    const float* x       = (const float*)d_in[0];
    const float* gat_W   = (const float*)d_in[2];
    const float* att_src = (const float*)d_in[3];
    const float* att_dst = (const float*)d_in[4];
    const float* gat_b   = (const float*)d_in[5];
    const float* W1      = (const float*)d_in[6];
    const float* b1      = (const float*)d_in[7];
    const float* W2      = (const float*)d_in[8];
    const float* b2      = (const float*)d_in[9];
    const float* ln1_g   = (const float*)d_in[10];
    const float* ln1_b   = (const float*)d_in[11];
    const float* ln2_g   = (const float*)d_in[12];
    const float* ln2_b   = (const float*)d_in[13];
    float* out = (float*)d_out;

    // workspace carve (256B aligned)
    char* p = (char*)d_ws;
    auto carve = [&p](size_t bytes) { char* r = p; p += (bytes + 255) & ~(size_t)255; return r; };
    float*          gbuf = (float*)carve((size_t)N_TOT * 256 * 4);       // g_out, later ff
    unsigned short* x1b  = (unsigned short*)carve((size_t)N_TOT * 256 * 2); // xb, later x1 bf16
    unsigned short* z    = (unsigned short*)carve((size_t)N_HOPS * 2048 * 2); // z, later hid
    float*          a_s  = (float*)carve((size_t)N_TOT * 8 * 4);
    float*          a_d  = (float*)carve((size_t)N_TOT * 8 * 4);
    float*          wsrc = (float*)carve(2048 * 4);
    float*          wdst = (float*)carve(2048 * 4);
    unsigned short* WmT  = (unsigned short*)carve(256 * 256 * 2);
    unsigned short* B2T  = (unsigned short*)carve(256 * 2048 * 2);
    unsigned short* W1T  = (unsigned short*)carve((size_t)FFD * 256 * 2);
    unsigned short* W2T  = (unsigned short*)carve((size_t)256 * FFD * 2);
    unsigned short* hid  = z;  // reuse after hop GEMM

    // 1. weight prep + transposes to bf16 [N][K]
    hipLaunchKernelGGL(prep_w, dim3(256), dim3(256), 0, stream,
                       gat_W, att_src, att_dst, wsrc, wdst, WmT);
    hipLaunchKernelGGL(tconv, dim3(8, 8, 8), dim3(32, 8), 0, stream,
                       gat_W, B2T, 2048, 2048, 256, 256);          // B2T[c][h*256+d]
    hipLaunchKernelGGL(tconv, dim3(32, 8, 1), dim3(32, 8), 0, stream,
                       W1, W1T, 1024, 256, 0, 0);                  // W1T[n][k]
    hipLaunchKernelGGL(tconv, dim3(8, 32, 1), dim3(32, 8), 0, stream,
                       W2, W2T, 256, 1024, 0, 0);                  // W2T[n][k]
    // 2. x -> bf16 (into x1b; consumed before ln1 overwrites it)
    hipLaunchKernelGGL(cvt_bf16, dim3(N_TOT * 256 / 4 / 256), dim3(256), 0, stream,
                       x, x1b, N_TOT * 256 / 4);
    // 3. attention logits
    hipLaunchKernelGGL(a_proj, dim3(N_TOT / 4), dim3(256), 0, stream,
                       x, wsrc, wdst, a_s, a_d);
    // 4. hop softmax + aggregation (bf16 z)
    hipLaunchKernelGGL(hop_z, dim3(N_HOPS), dim3(256), 0, stream,
                       x, a_s, a_d, z);
    // 5. g_all = x @ Wm + bias
    hipLaunchKernelGGL((gemm_bt<0, 0>), dim3(2, N_TOT / 128), dim3(256), 0, stream,
                       x1b, WmT, gat_b, gbuf, N_TOT, 256, 256);
    // 6. g_hop = z @ B2 + bias (overwrites rows 0..4095)
    hipLaunchKernelGGL((gemm_bt<0, 0>), dim3(2, N_HOPS / 128), dim3(256), 0, stream,
                       z, B2T, gat_b, gbuf, N_HOPS, 256, 2048);
    // 7. x1 = LN(g + x)  (bf16)
    hipLaunchKernelGGL((ln_add<0, 1>), dim3(N_TOT / 4), dim3(256), 0, stream,
                       gbuf, x, ln1_g, ln1_b, x1b);
    // 8. FFN in 8192-row chunks (hid reuses z buffer)
    for (int c0 = 0; c0 < N_TOT; c0 += CHUNK) {
        int Mc = (N_TOT - c0) < CHUNK ? (N_TOT - c0) : CHUNK;
        hipLaunchKernelGGL((gemm_bt<1, 1>), dim3(FFD / 128, Mc / 128), dim3(256), 0, stream,
                           x1b + (size_t)c0 * 256, W1T, b1, hid, Mc, FFD, 256);
        hipLaunchKernelGGL((gemm_bt<0, 0>), dim3(2, Mc / 128), dim3(256), 0, stream,
                           hid, W2T, b2, gbuf + (size_t)c0 * 256, Mc, 256, FFD);
    }
    // 9. out = LN(ff + x1)
    hipLaunchKernelGGL((ln_add<1, 0>), dim3(N_TOT / 4), dim3(256), 0, stream,
                       gbuf, x1b, ln2_g, ln2_b, out);
    (void)in_sizes; (void)n_in; (void)out_size; (void)ws_size;
}

// Round 3
// 432.383 us; speedup vs baseline: 3.8767x; 1.1898x over previous
//
#include <hip/hip_runtime.h>
#include <cstdint>
#include <cstddef>

#define N_TOT   53248
#define N_HOPS  4096
#define HOP_LEN 12
#define NHEAD   8
#define FFD     1024
#define CHUNK   8192
#define GLD     384     // gbuf leading dim: 256 (Wm/g_out) + 8 a_s + 8 a_d + pad

typedef __bf16 bf16x8 __attribute__((ext_vector_type(8)));
typedef float f32x4 __attribute__((ext_vector_type(4)));

__device__ __forceinline__ unsigned short f2bf(float f) {
    unsigned int u = __float_as_uint(f);
    u += 0x7FFFu + ((u >> 16) & 1u);
    return (unsigned short)(u >> 16);
}
__device__ __forceinline__ float bf2f(unsigned short b) {
    return __uint_as_float((unsigned int)b << 16);
}
__device__ __forceinline__ void gload16(const void* g, void* l) {
    __builtin_amdgcn_global_load_lds(
        (const __attribute__((address_space(1))) void*)g,
        (__attribute__((address_space(3))) void*)l, 16, 0, 0);
}

// ---------------------------------------------------------------------------
// prep: BcT[c][d]      = bf16( (1/8) sum_h W[d][h*256+c] )        (rows 0-255)
//       BcT[256+h][d]  = bf16( sum_c W[d][h*256+c]*att_s[h][c] )  (rows 256-263)
//       BcT[264+h][d]  = bf16( sum_c W[d][h*256+c]*att_d[h][c] )  (rows 264-271)
// rows 272-383 zeroed by memset. grid = 256 (d), block = 256 (c)
// ---------------------------------------------------------------------------
__global__ __launch_bounds__(256) void prep_w(
    const float* __restrict__ W, const float* __restrict__ att_s,
    const float* __restrict__ att_d, unsigned short* __restrict__ BcT)
{
    int d = blockIdx.x, c = threadIdx.x;
    int wave = c >> 6;
    __shared__ float ps4[4], pd4[4];
    float wm = 0.f;
    for (int h = 0; h < NHEAD; ++h) {
        float w = W[d * 2048 + h * 256 + c];
        wm += w;
        float ps = w * att_s[h * 256 + c];
        float pd = w * att_d[h * 256 + c];
        for (int o = 32; o > 0; o >>= 1) {
            ps += __shfl_xor(ps, o);
            pd += __shfl_xor(pd, o);
        }
        if ((c & 63) == 0) { ps4[wave] = ps; pd4[wave] = pd; }
        __syncthreads();
        if (c == 0) BcT[(256 + h) * 256 + d] = f2bf(ps4[0] + ps4[1] + ps4[2] + ps4[3]);
        if (c == 1) BcT[(264 + h) * 256 + d] = f2bf(pd4[0] + pd4[1] + pd4[2] + pd4[3]);
        __syncthreads();
    }
    BcT[c * 256 + d] = f2bf(wm * 0.125f);
}

// ---------------------------------------------------------------------------
// tiled transpose + f32->bf16: out[c*OS + r] = bf16(in[r*IS + c])
// ---------------------------------------------------------------------------
__global__ __launch_bounds__(256) void tconv(
    const float* __restrict__ in, unsigned short* __restrict__ out,
    int IS, int OS, int in_zoff, int out_zoff)
{
    __shared__ float t[32][33];
    in  += (size_t)blockIdx.z * in_zoff;
    out += (size_t)blockIdx.z * out_zoff;
    int tx = threadIdx.x, ty = threadIdx.y;
    int c0 = blockIdx.x * 32, r0 = blockIdx.y * 32;
    #pragma unroll
    for (int k = 0; k < 4; ++k)
        t[ty + 8 * k][tx] = in[(size_t)(r0 + ty + 8 * k) * IS + c0 + tx];
    __syncthreads();
    #pragma unroll
    for (int k = 0; k < 4; ++k)
        out[(size_t)(c0 + ty + 8 * k) * OS + r0 + tx] = f2bf(t[tx][ty + 8 * k]);
}

// ---------------------------------------------------------------------------
__global__ __launch_bounds__(256) void cvt_bf16(
    const float* __restrict__ in, unsigned short* __restrict__ out, int n4)
{
    int i = blockIdx.x * 256 + threadIdx.x;
    if (i >= n4) return;
    float4 v = ((const float4*)in)[i];
    ushort4 o;
    o.x = f2bf(v.x); o.y = f2bf(v.y); o.z = f2bf(v.z); o.w = f2bf(v.w);
    ((ushort4*)out)[i] = o;
}

// ---------------------------------------------------------------------------
// hop softmax + weighted x aggregation.
// Logits live in gbuf cols 256..271 (from combined GEMM). x read as bf16.
// z[j][h*256+d] = bf16( sum_e alpha[e,h]/8 * x[src_e][d] )
// grid = 4096 (j), block = 256
// ---------------------------------------------------------------------------
__global__ __launch_bounds__(256) void hop_z(
    const unsigned short* __restrict__ xb, const float* __restrict__ gb,
    unsigned short* __restrict__ z)
{
    int j = blockIdx.x, tid = threadIdx.x;
    __shared__ float xr[13][256];
    __shared__ float sm[NHEAD][13];
    __shared__ float walpha[NHEAD][13];
    __shared__ float mxs[NHEAD], invs[NHEAD];

    // load 13 bf16 rows (row 0 = hop j, rows 1..12 = members)
    for (int i = tid; i < 13 * 32; i += 256) {
        int r = i >> 5, c8 = (i & 31) * 8;
        int src = (r == 0) ? j : (N_HOPS + j * HOP_LEN + r - 1);
        uint4 u = *(const uint4*)&xb[(size_t)src * 256 + c8];
        float4 lo, hi;
        lo.x = bf2f((unsigned short)(u.x & 0xFFFF)); lo.y = bf2f((unsigned short)(u.x >> 16));
        lo.z = bf2f((unsigned short)(u.y & 0xFFFF)); lo.w = bf2f((unsigned short)(u.y >> 16));
        hi.x = bf2f((unsigned short)(u.z & 0xFFFF)); hi.y = bf2f((unsigned short)(u.z >> 16));
        hi.z = bf2f((unsigned short)(u.w & 0xFFFF)); hi.w = bf2f((unsigned short)(u.w >> 16));
        *(float4*)&xr[r][c8] = lo;
        *(float4*)&xr[r][c8 + 4] = hi;
    }
    // logits: t = h*13 + k, k=0 self, k>=1 member k-1
    if (tid < NHEAD * 13) {
        int h = tid / 13, k = tid % 13;
        int src = (k == 0) ? j : (N_HOPS + j * HOP_LEN + k - 1);
        float ad = gb[(size_t)j * GLD + 264 + h];
        float v = gb[(size_t)src * GLD + 256 + h] + ad;
        sm[h][k] = v > 0.f ? v : 0.2f * v;
    }
    __syncthreads();
    if (tid < NHEAD) {
        int h = tid;
        float mx = sm[h][0];
        for (int k = 1; k < 13; ++k) mx = fmaxf(mx, sm[h][k]);
        float sum = 2.f * expf(sm[h][0] - mx);   // self edge counted twice
        for (int k = 1; k < 13; ++k) sum += expf(sm[h][k] - mx);
        mxs[h] = mx;
        invs[h] = 0.125f / (sum + 1e-16f);
    }
    __syncthreads();
    if (tid < NHEAD * 13) {
        int h = tid / 13, k = tid % 13;
        walpha[h][k] = (k == 0 ? 2.f : 1.f) * expf(sm[h][k] - mxs[h]) * invs[h];
    }
    __syncthreads();
    for (int h = 0; h < NHEAD; ++h) {
        float acc = 0.f;
        #pragma unroll
        for (int r = 0; r < 13; ++r) acc += walpha[h][r] * xr[r][tid];
        z[((size_t)j * NHEAD + h) * 256 + tid] = f2bf(acc);
    }
}

// ---------------------------------------------------------------------------
// bf16 MFMA GEMM: C[M,Nc](ldc) = A[M,K](bf16) @ BT[Nc,K](bf16)^T + bias
// 128x128 tile, BK=32, 256 threads (4 waves 2x2), m97 structure.
// ---------------------------------------------------------------------------
template <int RELU, int OUT_BF16>
__global__ __launch_bounds__(256) void gemm_bt(
    const unsigned short* __restrict__ A, const unsigned short* __restrict__ BT,
    const float* __restrict__ bias, void* __restrict__ Cout,
    int M, int Nc, int K, int ldc)
{
    __shared__ __align__(16) unsigned short As[128 * 32];
    __shared__ __align__(16) unsigned short Bs[128 * 32];
    const int tid = threadIdx.x;
    const int l = tid & 63;
    const int bm = blockIdx.y * 128, bn = blockIdx.x * 128;
    const int wm = ((tid >> 6) >> 1) * 64, wn = ((tid >> 6) & 1) * 64;

    const int r0 = tid >> 2, ke0 = (tid & 3) * 8;
    const int r1 = (256 + tid) >> 2, ke1 = ((256 + tid) & 3) * 8;
    const unsigned short* ga0 = A + (size_t)(bm + r0) * K + ke0;
    const unsigned short* ga1 = A + (size_t)(bm + r1) * K + ke1;
    const unsigned short* gb0 = BT + (size_t)(bn + r0) * K + ke0;
    const unsigned short* gb1 = BT + (size_t)(bn + r1) * K + ke1;

    f32x4 acc[4][4];
    #pragma unroll
    for (int m = 0; m < 4; ++m)
        #pragma unroll
        for (int n = 0; n < 4; ++n)
            acc[m][n] = (f32x4){0.f, 0.f, 0.f, 0.f};

    const int lrow = l & 15, lk8 = (l >> 4) * 8;

    for (int k0 = 0; k0 < K; k0 += 32) {
        gload16(ga0 + k0, &As[(size_t)tid * 8]);
        gload16(ga1 + k0, &As[(size_t)(256 + tid) * 8]);
        gload16(gb0 + k0, &Bs[(size_t)tid * 8]);
        gload16(gb1 + k0, &Bs[(size_t)(256 + tid) * 8]);
        __syncthreads();
        bf16x8 af[4], bfr[4];
        #pragma unroll
        for (int m = 0; m < 4; ++m)
            af[m] = *(const bf16x8*)&As[(wm + m * 16 + lrow) * 32 + lk8];
        #pragma unroll
        for (int n = 0; n < 4; ++n)
            bfr[n] = *(const bf16x8*)&Bs[(wn + n * 16 + lrow) * 32 + lk8];
        #pragma unroll
        for (int m = 0; m < 4; ++m)
            #pragma unroll
            for (int n = 0; n < 4; ++n)
                acc[m][n] = __builtin_amdgcn_mfma_f32_16x16x32_bf16(
                    af[m], bfr[n], acc[m][n], 0, 0, 0);
        __syncthreads();
    }

    const int orow = (l >> 4) * 4, ocol = l & 15;
    #pragma unroll
    for (int m = 0; m < 4; ++m) {
        int gr = bm + wm + m * 16 + orow;
        #pragma unroll
        for (int n = 0; n < 4; ++n) {
            int gc = bn + wn + n * 16 + ocol;
            float bv = bias[gc];
            #pragma unroll
            for (int r = 0; r < 4; ++r) {
                float v = acc[m][n][r] + bv;
                if (RELU) v = fmaxf(v, 0.f);
                if (OUT_BF16)
                    ((unsigned short*)Cout)[(size_t)(gr + r) * ldc + gc] = f2bf(v);
                else
                    ((float*)Cout)[(size_t)(gr + r) * ldc + gc] = v;
            }
        }
    }
}

// ---------------------------------------------------------------------------
// out = LayerNorm(a + b) * g + be; a fp32 stride lda, b bf16 stride 256.
// one wave per row, float4/ushort4 vector loads.
// ---------------------------------------------------------------------------
template <int OUT_BF16>
__global__ __launch_bounds__(256) void ln_add(
    const float* __restrict__ a, int lda4,
    const unsigned short* __restrict__ b,
    const float* __restrict__ g, const float* __restrict__ be,
    void* __restrict__ outv)
{
    int wave = threadIdx.x >> 6, lane = threadIdx.x & 63;
    int n = blockIdx.x * 4 + wave;
    float4 av = ((const float4*)a)[(size_t)n * lda4 + lane];
    ushort4 bv = ((const ushort4*)b)[(size_t)n * 64 + lane];
    float v[4];
    v[0] = av.x + bf2f(bv.x); v[1] = av.y + bf2f(bv.y);
    v[2] = av.z + bf2f(bv.z); v[3] = av.w + bf2f(bv.w);
    float s = v[0] + v[1] + v[2] + v[3];
    for (int o = 32; o > 0; o >>= 1) s += __shfl_xor(s, o);
    float mu = s * (1.f / 256.f);
    float q = 0.f;
    #pragma unroll
    for (int i = 0; i < 4; ++i) { float d = v[i] - mu; q += d * d; }
    for (int o = 32; o > 0; o >>= 1) q += __shfl_xor(q, o);
    float rstd = rsqrtf(q * (1.f / 256.f) + 1e-5f);
    int c = lane * 4;
    float4 gv = *(const float4*)&g[c];
    float4 bev = *(const float4*)&be[c];
    float r0 = (v[0] - mu) * rstd * gv.x + bev.x;
    float r1 = (v[1] - mu) * rstd * gv.y + bev.y;
    float r2 = (v[2] - mu) * rstd * gv.z + bev.z;
    float r3 = (v[3] - mu) * rstd * gv.w + bev.w;
    if (OUT_BF16) {
        ushort4 o4 = { f2bf(r0), f2bf(r1), f2bf(r2), f2bf(r3) };
        ((ushort4*)outv)[(size_t)n * 64 + lane] = o4;
    } else {
        float4 o4 = { r0, r1, r2, r3 };
        ((float4*)outv)[(size_t)n * 64 + lane] = o4;
    }
}

// ---------------------------------------------------------------------------
extern "C" void kernel_launch(void* const* d_in, const int* in_sizes, int n_in,
                              void* d_out, int out_size, void* d_ws, size_t ws_size,
                              hipStream_t stream)
{
    const float* x       = (const float*)d_in[0];
    const float* gat_W   = (const float*)d_in[2];
    const float* att_src = (const float*)d_in[3];
    const float* att_dst = (const float*)d_in[4];
    const float* gat_b   = (const float*)d_in[5];
    const float* W1      = (const float*)d_in[6];
    const float* b1      = (const float*)d_in[7];
    const float* W2      = (const float*)d_in[8];
    const float* b2      = (const float*)d_in[9];
    const float* ln1_g   = (const float*)d_in[10];
    const float* ln1_b   = (const float*)d_in[11];
    const float* ln2_g   = (const float*)d_in[12];
    const float* ln2_b   = (const float*)d_in[13];
    float* out = (float*)d_out;

    char* p = (char*)d_ws;
    auto carve = [&p](size_t bytes) { char* r = p; p += (bytes + 255) & ~(size_t)255; return r; };
    float*          gbuf = (float*)carve((size_t)N_TOT * GLD * 4);          // [N][384]
    unsigned short* x1b  = (unsigned short*)carve((size_t)N_TOT * 256 * 2); // xb -> x1
    unsigned short* z    = (unsigned short*)carve((size_t)N_HOPS * 2048 * 2); // z -> hid
    unsigned short* BcT  = (unsigned short*)carve((size_t)GLD * 256 * 2);   // [384][256]
    unsigned short* B2T  = (unsigned short*)carve((size_t)2048 * 256 * 2);
    unsigned short* W1T  = (unsigned short*)carve((size_t)FFD * 256 * 2);
    unsigned short* W2T  = (unsigned short*)carve((size_t)256 * FFD * 2);
    float*          bias384 = (float*)carve(GLD * 4);
    unsigned short* hid  = z;

    // 0. small prep: pad rows of BcT = 0; bias384 = [gat_b | zeros]
    hipMemsetAsync(BcT + 272 * 256, 0, (size_t)(GLD - 272) * 256 * 2, stream);
    hipMemcpyAsync(bias384, gat_b, 256 * 4, hipMemcpyDeviceToDevice, stream);
    hipMemsetAsync(bias384 + 256, 0, (GLD - 256) * 4, stream);
    // 1. weight prep + transposes
    hipLaunchKernelGGL(prep_w, dim3(256), dim3(256), 0, stream,
                       gat_W, att_src, att_dst, BcT);
    hipLaunchKernelGGL(tconv, dim3(8, 8, 8), dim3(32, 8), 0, stream,
                       gat_W, B2T, 2048, 2048, 256, 256);
    hipLaunchKernelGGL(tconv, dim3(32, 8, 1), dim3(32, 8), 0, stream,
                       W1, W1T, 1024, 256, 0, 0);
    hipLaunchKernelGGL(tconv, dim3(8, 32, 1), dim3(32, 8), 0, stream,
                       W2, W2T, 256, 1024, 0, 0);
    // 2. x -> bf16
    hipLaunchKernelGGL(cvt_bf16, dim3(N_TOT * 256 / 4 / 256), dim3(256), 0, stream,
                       x, x1b, N_TOT * 256 / 4);
    // 3. combined GEMM: gbuf[n][0:256]=x@Wm+gat_b, [256:272]=attn logits
    hipLaunchKernelGGL((gemm_bt<0, 0>), dim3(GLD / 128, N_TOT / 128), dim3(256), 0, stream,
                       x1b, BcT, bias384, gbuf, N_TOT, GLD, 256, GLD);
    // 4. hop softmax + aggregation
    hipLaunchKernelGGL(hop_z, dim3(N_HOPS), dim3(256), 0, stream,
                       x1b, gbuf, z);
    // 5. g_hop = z @ B2 + bias (rows 0..4095, cols 0..255 of gbuf)
    hipLaunchKernelGGL((gemm_bt<0, 0>), dim3(2, N_HOPS / 128), dim3(256), 0, stream,
                       z, B2T, gat_b, gbuf, N_HOPS, 256, 2048, GLD);
    // 6. x1 = LN(g + x) -> bf16 (in place over x1b)
    hipLaunchKernelGGL((ln_add<1>), dim3(N_TOT / 4), dim3(256), 0, stream,
                       gbuf, GLD / 4, x1b, ln1_g, ln1_b, x1b);
    // 7. FFN chunks (hid reuses z)
    for (int c0 = 0; c0 < N_TOT; c0 += CHUNK) {
        int Mc = (N_TOT - c0) < CHUNK ? (N_TOT - c0) : CHUNK;
        hipLaunchKernelGGL((gemm_bt<1, 1>), dim3(FFD / 128, Mc / 128), dim3(256), 0, stream,
                           x1b + (size_t)c0 * 256, W1T, b1, hid, Mc, FFD, 256, FFD);
        hipLaunchKernelGGL((gemm_bt<0, 0>), dim3(2, Mc / 128), dim3(256), 0, stream,
                           hid, W2T, b2, gbuf + (size_t)c0 * GLD, Mc, 256, FFD, GLD);
    }
    // 8. out = LN(ff + x1) -> fp32
    hipLaunchKernelGGL((ln_add<0>), dim3(N_TOT / 4), dim3(256), 0, stream,
                       gbuf, GLD / 4, x1b, ln2_g, ln2_b, out);
    (void)in_sizes; (void)n_in; (void)out_size; (void)ws_size;
}

// Round 4
// 259.165 us; speedup vs baseline: 6.4678x; 1.6684x over previous
//
#include <hip/hip_runtime.h>
#include <cstdint>
#include <cstddef>

#define N_TOT   53248
#define N_HOPS  4096
#define HOP_LEN 12
#define NHEAD   8
#define FFD     1024
#define CHUNK   8192
#define GLD     384     // gbuf leading dim: 256 (Wm/g_out) + 8 a_s + 8 a_d + pad

typedef __bf16 bf16x8 __attribute__((ext_vector_type(8)));
typedef float f32x4 __attribute__((ext_vector_type(4)));

__device__ __forceinline__ unsigned short f2bf(float f) {
    unsigned int u = __float_as_uint(f);
    u += 0x7FFFu + ((u >> 16) & 1u);
    return (unsigned short)(u >> 16);
}
__device__ __forceinline__ float bf2f(unsigned short b) {
    return __uint_as_float((unsigned int)b << 16);
}
__device__ __forceinline__ void gload16(const void* g, void* l) {
    __builtin_amdgcn_global_load_lds(
        (const __attribute__((address_space(1))) void*)g,
        (__attribute__((address_space(3))) void*)l, 16, 0, 0);
}

// ---------------------------------------------------------------------------
// prep: BcT rows 0-255 = Wm^T (bf16), rows 256-263 = wsrc^T, 264-271 = wdst^T
// ---------------------------------------------------------------------------
__global__ __launch_bounds__(256) void prep_w(
    const float* __restrict__ W, const float* __restrict__ att_s,
    const float* __restrict__ att_d, unsigned short* __restrict__ BcT)
{
    int d = blockIdx.x, c = threadIdx.x;
    int wave = c >> 6;
    __shared__ float ps4[4], pd4[4];
    float wm = 0.f;
    for (int h = 0; h < NHEAD; ++h) {
        float w = W[d * 2048 + h * 256 + c];
        wm += w;
        float ps = w * att_s[h * 256 + c];
        float pd = w * att_d[h * 256 + c];
        for (int o = 32; o > 0; o >>= 1) {
            ps += __shfl_xor(ps, o);
            pd += __shfl_xor(pd, o);
        }
        if ((c & 63) == 0) { ps4[wave] = ps; pd4[wave] = pd; }
        __syncthreads();
        if (c == 0) BcT[(256 + h) * 256 + d] = f2bf(ps4[0] + ps4[1] + ps4[2] + ps4[3]);
        if (c == 1) BcT[(264 + h) * 256 + d] = f2bf(pd4[0] + pd4[1] + pd4[2] + pd4[3]);
        __syncthreads();
    }
    BcT[c * 256 + d] = f2bf(wm * 0.125f);
}

// ---------------------------------------------------------------------------
__global__ __launch_bounds__(256) void tconv(
    const float* __restrict__ in, unsigned short* __restrict__ out,
    int IS, int OS, int in_zoff, int out_zoff)
{
    __shared__ float t[32][33];
    in  += (size_t)blockIdx.z * in_zoff;
    out += (size_t)blockIdx.z * out_zoff;
    int tx = threadIdx.x, ty = threadIdx.y;
    int c0 = blockIdx.x * 32, r0 = blockIdx.y * 32;
    #pragma unroll
    for (int k = 0; k < 4; ++k)
        t[ty + 8 * k][tx] = in[(size_t)(r0 + ty + 8 * k) * IS + c0 + tx];
    __syncthreads();
    #pragma unroll
    for (int k = 0; k < 4; ++k)
        out[(size_t)(c0 + ty + 8 * k) * OS + r0 + tx] = f2bf(t[tx][ty + 8 * k]);
}

// ---------------------------------------------------------------------------
__global__ __launch_bounds__(256) void cvt_bf16(
    const float* __restrict__ in, unsigned short* __restrict__ out, int n4)
{
    int i = blockIdx.x * 256 + threadIdx.x;
    if (i >= n4) return;
    float4 v = ((const float4*)in)[i];
    ushort4 o;
    o.x = f2bf(v.x); o.y = f2bf(v.y); o.z = f2bf(v.z); o.w = f2bf(v.w);
    ((ushort4*)out)[i] = o;
}

// ---------------------------------------------------------------------------
// hop softmax + weighted x aggregation (logits from gbuf cols 256..271)
// ---------------------------------------------------------------------------
__global__ __launch_bounds__(256) void hop_z(
    const unsigned short* __restrict__ xb, const float* __restrict__ gb,
    unsigned short* __restrict__ z)
{
    int j = blockIdx.x, tid = threadIdx.x;
    __shared__ float xr[13][256];
    __shared__ float sm[NHEAD][13];
    __shared__ float walpha[NHEAD][13];
    __shared__ float mxs[NHEAD], invs[NHEAD];

    for (int i = tid; i < 13 * 32; i += 256) {
        int r = i >> 5, c8 = (i & 31) * 8;
        int src = (r == 0) ? j : (N_HOPS + j * HOP_LEN + r - 1);
        uint4 u = *(const uint4*)&xb[(size_t)src * 256 + c8];
        float4 lo, hi;
        lo.x = bf2f((unsigned short)(u.x & 0xFFFF)); lo.y = bf2f((unsigned short)(u.x >> 16));
        lo.z = bf2f((unsigned short)(u.y & 0xFFFF)); lo.w = bf2f((unsigned short)(u.y >> 16));
        hi.x = bf2f((unsigned short)(u.z & 0xFFFF)); hi.y = bf2f((unsigned short)(u.z >> 16));
        hi.z = bf2f((unsigned short)(u.w & 0xFFFF)); hi.w = bf2f((unsigned short)(u.w >> 16));
        *(float4*)&xr[r][c8] = lo;
        *(float4*)&xr[r][c8 + 4] = hi;
    }
    if (tid < NHEAD * 13) {
        int h = tid / 13, k = tid % 13;
        int src = (k == 0) ? j : (N_HOPS + j * HOP_LEN + k - 1);
        float ad = gb[(size_t)j * GLD + 264 + h];
        float v = gb[(size_t)src * GLD + 256 + h] + ad;
        sm[h][k] = v > 0.f ? v : 0.2f * v;
    }
    __syncthreads();
    if (tid < NHEAD) {
        int h = tid;
        float mx = sm[h][0];
        for (int k = 1; k < 13; ++k) mx = fmaxf(mx, sm[h][k]);
        float sum = 2.f * expf(sm[h][0] - mx);   // self edge counted twice
        for (int k = 1; k < 13; ++k) sum += expf(sm[h][k] - mx);
        mxs[h] = mx;
        invs[h] = 0.125f / (sum + 1e-16f);
    }
    __syncthreads();
    if (tid < NHEAD * 13) {
        int h = tid / 13, k = tid % 13;
        walpha[h][k] = (k == 0 ? 2.f : 1.f) * expf(sm[h][k] - mxs[h]) * invs[h];
    }
    __syncthreads();
    for (int h = 0; h < NHEAD; ++h) {
        float acc = 0.f;
        #pragma unroll
        for (int r = 0; r < 13; ++r) acc += walpha[h][r] * xr[r][tid];
        z[((size_t)j * NHEAD + h) * 256 + tid] = f2bf(acc);
    }
}

// ---------------------------------------------------------------------------
// bf16 MFMA GEMM (m97 structure): C[M,Nc](ldc) = A @ BT^T + bias
// ---------------------------------------------------------------------------
template <int RELU, int OUT_BF16>
__global__ __launch_bounds__(256) void gemm_bt(
    const unsigned short* __restrict__ A, const unsigned short* __restrict__ BT,
    const float* __restrict__ bias, void* __restrict__ Cout,
    int M, int Nc, int K, int ldc)
{
    __shared__ __align__(16) unsigned short As[128 * 32];
    __shared__ __align__(16) unsigned short Bs[128 * 32];
    const int tid = threadIdx.x;
    const int l = tid & 63;
    const int bm = blockIdx.y * 128, bn = blockIdx.x * 128;
    const int wm = ((tid >> 6) >> 1) * 64, wn = ((tid >> 6) & 1) * 64;

    const int r0 = tid >> 2, ke0 = (tid & 3) * 8;
    const int r1 = (256 + tid) >> 2, ke1 = ((256 + tid) & 3) * 8;
    const unsigned short* ga0 = A + (size_t)(bm + r0) * K + ke0;
    const unsigned short* ga1 = A + (size_t)(bm + r1) * K + ke1;
    const unsigned short* gb0 = BT + (size_t)(bn + r0) * K + ke0;
    const unsigned short* gb1 = BT + (size_t)(bn + r1) * K + ke1;

    f32x4 acc[4][4];
    #pragma unroll
    for (int m = 0; m < 4; ++m)
        #pragma unroll
        for (int n = 0; n < 4; ++n)
            acc[m][n] = (f32x4){0.f, 0.f, 0.f, 0.f};

    const int lrow = l & 15, lk8 = (l >> 4) * 8;

    for (int k0 = 0; k0 < K; k0 += 32) {
        gload16(ga0 + k0, &As[(size_t)tid * 8]);
        gload16(ga1 + k0, &As[(size_t)(256 + tid) * 8]);
        gload16(gb0 + k0, &Bs[(size_t)tid * 8]);
        gload16(gb1 + k0, &Bs[(size_t)(256 + tid) * 8]);
        __syncthreads();
        bf16x8 af[4], bfr[4];
        #pragma unroll
        for (int m = 0; m < 4; ++m)
            af[m] = *(const bf16x8*)&As[(wm + m * 16 + lrow) * 32 + lk8];
        #pragma unroll
        for (int n = 0; n < 4; ++n)
            bfr[n] = *(const bf16x8*)&Bs[(wn + n * 16 + lrow) * 32 + lk8];
        #pragma unroll
        for (int m = 0; m < 4; ++m)
            #pragma unroll
            for (int n = 0; n < 4; ++n)
                acc[m][n] = __builtin_amdgcn_mfma_f32_16x16x32_bf16(
                    af[m], bfr[n], acc[m][n], 0, 0, 0);
        __syncthreads();
    }

    const int orow = (l >> 4) * 4, ocol = l & 15;
    #pragma unroll
    for (int m = 0; m < 4; ++m) {
        int gr = bm + wm + m * 16 + orow;
        #pragma unroll
        for (int n = 0; n < 4; ++n) {
            int gc = bn + wn + n * 16 + ocol;
            float bv = bias[gc];
            #pragma unroll
            for (int r = 0; r < 4; ++r) {
                float v = acc[m][n][r] + bv;
                if (RELU) v = fmaxf(v, 0.f);
                if (OUT_BF16)
                    ((unsigned short*)Cout)[(size_t)(gr + r) * ldc + gc] = f2bf(v);
                else
                    ((float*)Cout)[(size_t)(gr + r) * ldc + gc] = v;
            }
        }
    }
}

// ---------------------------------------------------------------------------
// split-K variant: partial[z][M][Nc] (bf16) = A[:, z*Ksl:(z+1)*Ksl] @ BT^T
// A rows stride ldA, BT rows stride ldA. No bias, no relu.
// ---------------------------------------------------------------------------
__global__ __launch_bounds__(256) void gemm_bt_sk(
    const unsigned short* __restrict__ A, const unsigned short* __restrict__ BT,
    unsigned short* __restrict__ Cpart, int M, int Nc, int Ksl, int ldA)
{
    __shared__ __align__(16) unsigned short As[128 * 32];
    __shared__ __align__(16) unsigned short Bs[128 * 32];
    const int tid = threadIdx.x;
    const int l = tid & 63;
    const int bm = blockIdx.y * 128, bn = blockIdx.x * 128;
    const int koff = blockIdx.z * Ksl;
    const int wm = ((tid >> 6) >> 1) * 64, wn = ((tid >> 6) & 1) * 64;

    const int r0 = tid >> 2, ke0 = (tid & 3) * 8;
    const int r1 = (256 + tid) >> 2, ke1 = ((256 + tid) & 3) * 8;
    const unsigned short* ga0 = A + (size_t)(bm + r0) * ldA + koff + ke0;
    const unsigned short* ga1 = A + (size_t)(bm + r1) * ldA + koff + ke1;
    const unsigned short* gb0 = BT + (size_t)(bn + r0) * ldA + koff + ke0;
    const unsigned short* gb1 = BT + (size_t)(bn + r1) * ldA + koff + ke1;

    f32x4 acc[4][4];
    #pragma unroll
    for (int m = 0; m < 4; ++m)
        #pragma unroll
        for (int n = 0; n < 4; ++n)
            acc[m][n] = (f32x4){0.f, 0.f, 0.f, 0.f};

    const int lrow = l & 15, lk8 = (l >> 4) * 8;

    for (int k0 = 0; k0 < Ksl; k0 += 32) {
        gload16(ga0 + k0, &As[(size_t)tid * 8]);
        gload16(ga1 + k0, &As[(size_t)(256 + tid) * 8]);
        gload16(gb0 + k0, &Bs[(size_t)tid * 8]);
        gload16(gb1 + k0, &Bs[(size_t)(256 + tid) * 8]);
        __syncthreads();
        bf16x8 af[4], bfr[4];
        #pragma unroll
        for (int m = 0; m < 4; ++m)
            af[m] = *(const bf16x8*)&As[(wm + m * 16 + lrow) * 32 + lk8];
        #pragma unroll
        for (int n = 0; n < 4; ++n)
            bfr[n] = *(const bf16x8*)&Bs[(wn + n * 16 + lrow) * 32 + lk8];
        #pragma unroll
        for (int m = 0; m < 4; ++m)
            #pragma unroll
            for (int n = 0; n < 4; ++n)
                acc[m][n] = __builtin_amdgcn_mfma_f32_16x16x32_bf16(
                    af[m], bfr[n], acc[m][n], 0, 0, 0);
        __syncthreads();
    }

    unsigned short* Cp = Cpart + (size_t)blockIdx.z * M * Nc;
    const int orow = (l >> 4) * 4, ocol = l & 15;
    #pragma unroll
    for (int m = 0; m < 4; ++m) {
        int gr = bm + wm + m * 16 + orow;
        #pragma unroll
        for (int n = 0; n < 4; ++n) {
            int gc = bn + wn + n * 16 + ocol;
            #pragma unroll
            for (int r = 0; r < 4; ++r)
                Cp[(size_t)(gr + r) * Nc + gc] = f2bf(acc[m][n][r]);
        }
    }
}

// ---------------------------------------------------------------------------
// hop reduce: gbuf[row][col] = sum_z hopP[z][row][col] + bias[col]
// 4 cols/thread; grid = N_HOPS*64/256
// ---------------------------------------------------------------------------
__global__ __launch_bounds__(256) void red_hop(
    const unsigned short* __restrict__ P, const float* __restrict__ bias,
    float* __restrict__ gbuf)
{
    int i = blockIdx.x * 256 + threadIdx.x;       // group of 4 cols
    int row = i >> 6, c4 = (i & 63) * 4;
    float4 s = { 0.f, 0.f, 0.f, 0.f };
    #pragma unroll
    for (int zz = 0; zz < 8; ++zz) {
        ushort4 u = *(const ushort4*)&P[(size_t)zz * N_HOPS * 256 + (size_t)row * 256 + c4];
        s.x += bf2f(u.x); s.y += bf2f(u.y); s.z += bf2f(u.z); s.w += bf2f(u.w);
    }
    float4 bv = *(const float4*)&bias[c4];
    s.x += bv.x; s.y += bv.y; s.z += bv.z; s.w += bv.w;
    *(float4*)&gbuf[(size_t)row * GLD + c4] = s;
}

// ---------------------------------------------------------------------------
// out = LayerNorm(a + b); a fp32 stride lda4*4, b bf16 stride 256
// ---------------------------------------------------------------------------
template <int OUT_BF16>
__global__ __launch_bounds__(256) void ln_add(
    const float* __restrict__ a, int lda4,
    const unsigned short* __restrict__ b,
    const float* __restrict__ g, const float* __restrict__ be,
    void* __restrict__ outv)
{
    int wave = threadIdx.x >> 6, lane = threadIdx.x & 63;
    int n = blockIdx.x * 4 + wave;
    float4 av = ((const float4*)a)[(size_t)n * lda4 + lane];
    ushort4 bv = ((const ushort4*)b)[(size_t)n * 64 + lane];
    float v[4];
    v[0] = av.x + bf2f(bv.x); v[1] = av.y + bf2f(bv.y);
    v[2] = av.z + bf2f(bv.z); v[3] = av.w + bf2f(bv.w);
    float s = v[0] + v[1] + v[2] + v[3];
    for (int o = 32; o > 0; o >>= 1) s += __shfl_xor(s, o);
    float mu = s * (1.f / 256.f);
    float q = 0.f;
    #pragma unroll
    for (int i = 0; i < 4; ++i) { float d = v[i] - mu; q += d * d; }
    for (int o = 32; o > 0; o >>= 1) q += __shfl_xor(q, o);
    float rstd = rsqrtf(q * (1.f / 256.f) + 1e-5f);
    int c = lane * 4;
    float4 gv = *(const float4*)&g[c];
    float4 bev = *(const float4*)&be[c];
    float r0 = (v[0] - mu) * rstd * gv.x + bev.x;
    float r1 = (v[1] - mu) * rstd * gv.y + bev.y;
    float r2 = (v[2] - mu) * rstd * gv.z + bev.z;
    float r3 = (v[3] - mu) * rstd * gv.w + bev.w;
    if (OUT_BF16) {
        ushort4 o4 = { f2bf(r0), f2bf(r1), f2bf(r2), f2bf(r3) };
        ((ushort4*)outv)[(size_t)n * 64 + lane] = o4;
    } else {
        float4 o4 = { r0, r1, r2, r3 };
        ((float4*)outv)[(size_t)n * 64 + lane] = o4;
    }
}

// ---------------------------------------------------------------------------
// out = LayerNorm(P0 + P1 + bias2 + res)  (split-K FFN2 epilogue, fp32 out)
// ---------------------------------------------------------------------------
__global__ __launch_bounds__(256) void ln_add_p(
    const unsigned short* __restrict__ P0, const unsigned short* __restrict__ P1,
    const float* __restrict__ b2, const unsigned short* __restrict__ res,
    const float* __restrict__ g, const float* __restrict__ be,
    float* __restrict__ out)
{
    int wave = threadIdx.x >> 6, lane = threadIdx.x & 63;
    int n = blockIdx.x * 4 + wave;
    size_t vidx = (size_t)n * 64 + lane;
    ushort4 p0 = ((const ushort4*)P0)[vidx];
    ushort4 p1 = ((const ushort4*)P1)[vidx];
    ushort4 rv = ((const ushort4*)res)[vidx];
    int c = lane * 4;
    float4 b2v = *(const float4*)&b2[c];
    float v[4];
    v[0] = bf2f(p0.x) + bf2f(p1.x) + b2v.x + bf2f(rv.x);
    v[1] = bf2f(p0.y) + bf2f(p1.y) + b2v.y + bf2f(rv.y);
    v[2] = bf2f(p0.z) + bf2f(p1.z) + b2v.z + bf2f(rv.z);
    v[3] = bf2f(p0.w) + bf2f(p1.w) + b2v.w + bf2f(rv.w);
    float s = v[0] + v[1] + v[2] + v[3];
    for (int o = 32; o > 0; o >>= 1) s += __shfl_xor(s, o);
    float mu = s * (1.f / 256.f);
    float q = 0.f;
    #pragma unroll
    for (int i = 0; i < 4; ++i) { float d = v[i] - mu; q += d * d; }
    for (int o = 32; o > 0; o >>= 1) q += __shfl_xor(q, o);
    float rstd = rsqrtf(q * (1.f / 256.f) + 1e-5f);
    float4 gv = *(const float4*)&g[c];
    float4 bev = *(const float4*)&be[c];
    float4 o4;
    o4.x = (v[0] - mu) * rstd * gv.x + bev.x;
    o4.y = (v[1] - mu) * rstd * gv.y + bev.y;
    o4.z = (v[2] - mu) * rstd * gv.z + bev.z;
    o4.w = (v[3] - mu) * rstd * gv.w + bev.w;
    ((float4*)out)[vidx] = o4;
}

// ---------------------------------------------------------------------------
extern "C" void kernel_launch(void* const* d_in, const int* in_sizes, int n_in,
                              void* d_out, int out_size, void* d_ws, size_t ws_size,
                              hipStream_t stream)
{
    const float* x       = (const float*)d_in[0];
    const float* gat_W   = (const float*)d_in[2];
    const float* att_src = (const float*)d_in[3];
    const float* att_dst = (const float*)d_in[4];
    const float* gat_b   = (const float*)d_in[5];
    const float* W1      = (const float*)d_in[6];
    const float* b1      = (const float*)d_in[7];
    const float* W2      = (const float*)d_in[8];
    const float* b2      = (const float*)d_in[9];
    const float* ln1_g   = (const float*)d_in[10];
    const float* ln1_b   = (const float*)d_in[11];
    const float* ln2_g   = (const float*)d_in[12];
    const float* ln2_b   = (const float*)d_in[13];
    float* out = (float*)d_out;

    char* p = (char*)d_ws;
    auto carve = [&p](size_t bytes) { char* r = p; p += (bytes + 255) & ~(size_t)255; return r; };
    float*          gbuf = (float*)carve((size_t)N_TOT * GLD * 4);          // [N][384]
    unsigned short* x1b  = (unsigned short*)carve((size_t)N_TOT * 256 * 2); // xb -> x1

    // full layout needs hid [N][1024] bf16 (z and hop partials alias its head)
    size_t fixed_tail = (size_t)GLD * 256 * 2 + (size_t)2048 * 256 * 2 +
                        (size_t)FFD * 256 * 2 + (size_t)256 * FFD * 2 + GLD * 4 + 8 * 256;
    size_t need_full = (size_t)(p - (char*)d_ws) + (size_t)N_TOT * FFD * 2 + fixed_tail;
    bool full = ws_size >= need_full;

    unsigned short* hid  = nullptr;   // full: [N][1024]
    unsigned short* z;                // [4096][2048]
    unsigned short* hopP;             // [8][4096][256] partials
    if (full) {
        hid  = (unsigned short*)carve((size_t)N_TOT * FFD * 2);
        z    = hid;                                   // alias: dead before FFN1
        hopP = hid + (size_t)N_HOPS * 2048;           // alias: dead before FFN1
    } else {
        z    = (unsigned short*)carve((size_t)N_HOPS * 2048 * 2);
        hopP = nullptr;
    }
    unsigned short* BcT  = (unsigned short*)carve((size_t)GLD * 256 * 2);
    unsigned short* B2T  = (unsigned short*)carve((size_t)2048 * 256 * 2);
    unsigned short* W1T  = (unsigned short*)carve((size_t)FFD * 256 * 2);
    unsigned short* W2T  = (unsigned short*)carve((size_t)256 * FFD * 2);
    float*          bias384 = (float*)carve(GLD * 4);
    // FFN2 split-K partials reuse gbuf (dead after ln1): 2 * N * 256 bf16 = 54.5MB
    unsigned short* ffP0 = (unsigned short*)gbuf;
    unsigned short* ffP1 = ffP0 + (size_t)N_TOT * 256;

    // 0. small prep
    hipMemsetAsync(BcT + 272 * 256, 0, (size_t)(GLD - 272) * 256 * 2, stream);
    hipMemcpyAsync(bias384, gat_b, 256 * 4, hipMemcpyDeviceToDevice, stream);
    hipMemsetAsync(bias384 + 256, 0, (GLD - 256) * 4, stream);
    // 1. weight prep + transposes
    hipLaunchKernelGGL(prep_w, dim3(256), dim3(256), 0, stream,
                       gat_W, att_src, att_dst, BcT);
    hipLaunchKernelGGL(tconv, dim3(8, 8, 8), dim3(32, 8), 0, stream,
                       gat_W, B2T, 2048, 2048, 256, 256);
    hipLaunchKernelGGL(tconv, dim3(32, 8, 1), dim3(32, 8), 0, stream,
                       W1, W1T, 1024, 256, 0, 0);
    hipLaunchKernelGGL(tconv, dim3(8, 32, 1), dim3(32, 8), 0, stream,
                       W2, W2T, 256, 1024, 0, 0);
    // 2. x -> bf16
    hipLaunchKernelGGL(cvt_bf16, dim3(N_TOT * 256 / 4 / 256), dim3(256), 0, stream,
                       x, x1b, N_TOT * 256 / 4);
    // 3. combined GEMM: g_out + attn logits
    hipLaunchKernelGGL((gemm_bt<0, 0>), dim3(GLD / 128, N_TOT / 128), dim3(256), 0, stream,
                       x1b, BcT, bias384, gbuf, N_TOT, GLD, 256, GLD);
    // 4. hop softmax + aggregation
    hipLaunchKernelGGL(hop_z, dim3(N_HOPS), dim3(256), 0, stream,
                       x1b, gbuf, z);
    // 5. g_hop = z @ B2 + bias
    if (full) {
        hipLaunchKernelGGL(gemm_bt_sk, dim3(2, N_HOPS / 128, 8), dim3(256), 0, stream,
                           z, B2T, hopP, N_HOPS, 256, 256, 2048);
        hipLaunchKernelGGL(red_hop, dim3(N_HOPS * 64 / 256), dim3(256), 0, stream,
                           hopP, gat_b, gbuf);
    } else {
        hipLaunchKernelGGL((gemm_bt<0, 0>), dim3(2, N_HOPS / 128), dim3(256), 0, stream,
                           z, B2T, gat_b, gbuf, N_HOPS, 256, 2048, GLD);
    }
    // 6. x1 = LN(g + x) -> bf16 (in place over x1b)
    hipLaunchKernelGGL((ln_add<1>), dim3(N_TOT / 4), dim3(256), 0, stream,
                       gbuf, GLD / 4, x1b, ln1_g, ln1_b, x1b);
    // 7+8. FFN + ln2
    if (full) {
        // FFN1 over all rows
        hipLaunchKernelGGL((gemm_bt<1, 1>), dim3(FFD / 128, N_TOT / 128), dim3(256), 0, stream,
                           x1b, W1T, b1, hid, N_TOT, FFD, 256, FFD);
        // FFN2 split-K=2, partials into gbuf region
        hipLaunchKernelGGL(gemm_bt_sk, dim3(2, N_TOT / 128, 2), dim3(256), 0, stream,
                           hid, W2T, ffP0, N_TOT, 256, 512, FFD);
        // out = LN(P0 + P1 + b2 + x1)
        hipLaunchKernelGGL(ln_add_p, dim3(N_TOT / 4), dim3(256), 0, stream,
                           ffP0, ffP1, b2, x1b, ln2_g, ln2_b, out);
    } else {
        unsigned short* hidc = z;  // chunked hidden reuses z
        for (int c0 = 0; c0 < N_TOT; c0 += CHUNK) {
            int Mc = (N_TOT - c0) < CHUNK ? (N_TOT - c0) : CHUNK;
            hipLaunchKernelGGL((gemm_bt<1, 1>), dim3(FFD / 128, Mc / 128), dim3(256), 0, stream,
                               x1b + (size_t)c0 * 256, W1T, b1, hidc, Mc, FFD, 256, FFD);
            hipLaunchKernelGGL((gemm_bt<0, 0>), dim3(2, Mc / 128), dim3(256), 0, stream,
                               hidc, W2T, b2, gbuf + (size_t)c0 * GLD, Mc, 256, FFD, GLD);
        }
        hipLaunchKernelGGL((ln_add<0>), dim3(N_TOT / 4), dim3(256), 0, stream,
                           gbuf, GLD / 4, x1b, ln2_g, ln2_b, out);
    }
    (void)in_sizes; (void)n_in; (void)out_size;
}

// Round 5
// 232.925 us; speedup vs baseline: 7.1964x; 1.1127x over previous
//
#include <hip/hip_runtime.h>
#include <cstdint>
#include <cstddef>

#define N_TOT   53248
#define N_HOPS  4096
#define HOP_LEN 12
#define NHEAD   8
#define FFD     1024
#define GLD     384     // gbuf leading dim: 256 (g_out) + 8 a_s + 8 a_d + pad

typedef __bf16 bf16x8 __attribute__((ext_vector_type(8)));
typedef float f32x4 __attribute__((ext_vector_type(4)));

__device__ __forceinline__ unsigned short f2bf(float f) {
    unsigned int u = __float_as_uint(f);
    u += 0x7FFFu + ((u >> 16) & 1u);
    return (unsigned short)(u >> 16);
}
__device__ __forceinline__ float bf2f(unsigned short b) {
    return __uint_as_float((unsigned int)b << 16);
}
__device__ __forceinline__ void gload16(const void* g, void* l) {
    __builtin_amdgcn_global_load_lds(
        (const __attribute__((address_space(1))) void*)g,
        (__attribute__((address_space(3))) void*)l, 16, 0, 0);
}

// ---------------------------------------------------------------------------
// prep: BcT rows 0-255 = Wm^T (bf16), rows 256-263 = wsrc^T, 264-271 = wdst^T
// ---------------------------------------------------------------------------
__global__ __launch_bounds__(256) void prep_w(
    const float* __restrict__ W, const float* __restrict__ att_s,
    const float* __restrict__ att_d, unsigned short* __restrict__ BcT)
{
    int d = blockIdx.x, c = threadIdx.x;
    int wave = c >> 6;
    __shared__ float ps4[4], pd4[4];
    float wm = 0.f;
    for (int h = 0; h < NHEAD; ++h) {
        float w = W[d * 2048 + h * 256 + c];
        wm += w;
        float ps = w * att_s[h * 256 + c];
        float pd = w * att_d[h * 256 + c];
        for (int o = 32; o > 0; o >>= 1) {
            ps += __shfl_xor(ps, o);
            pd += __shfl_xor(pd, o);
        }
        if ((c & 63) == 0) { ps4[wave] = ps; pd4[wave] = pd; }
        __syncthreads();
        if (c == 0) BcT[(256 + h) * 256 + d] = f2bf(ps4[0] + ps4[1] + ps4[2] + ps4[3]);
        if (c == 1) BcT[(264 + h) * 256 + d] = f2bf(pd4[0] + pd4[1] + pd4[2] + pd4[3]);
        __syncthreads();
    }
    BcT[c * 256 + d] = f2bf(wm * 0.125f);
}

// ---------------------------------------------------------------------------
__global__ __launch_bounds__(256) void tconv(
    const float* __restrict__ in, unsigned short* __restrict__ out,
    int IS, int OS, int in_zoff, int out_zoff)
{
    __shared__ float t[32][33];
    in  += (size_t)blockIdx.z * in_zoff;
    out += (size_t)blockIdx.z * out_zoff;
    int tx = threadIdx.x, ty = threadIdx.y;
    int c0 = blockIdx.x * 32, r0 = blockIdx.y * 32;
    #pragma unroll
    for (int k = 0; k < 4; ++k)
        t[ty + 8 * k][tx] = in[(size_t)(r0 + ty + 8 * k) * IS + c0 + tx];
    __syncthreads();
    #pragma unroll
    for (int k = 0; k < 4; ++k)
        out[(size_t)(c0 + ty + 8 * k) * OS + r0 + tx] = f2bf(t[tx][ty + 8 * k]);
}

// ---------------------------------------------------------------------------
__global__ __launch_bounds__(256) void cvt_bf16(
    const float* __restrict__ in, unsigned short* __restrict__ out, int n4)
{
    int i = blockIdx.x * 256 + threadIdx.x;
    if (i >= n4) return;
    float4 v = ((const float4*)in)[i];
    ushort4 o;
    o.x = f2bf(v.x); o.y = f2bf(v.y); o.z = f2bf(v.z); o.w = f2bf(v.w);
    ((ushort4*)out)[i] = o;
}

// ---------------------------------------------------------------------------
// hop softmax + weighted x aggregation (logits from bf16 gbuf cols 256..271)
// ---------------------------------------------------------------------------
__global__ __launch_bounds__(256) void hop_z(
    const unsigned short* __restrict__ xb, const unsigned short* __restrict__ gb,
    unsigned short* __restrict__ z)
{
    int j = blockIdx.x, tid = threadIdx.x;
    __shared__ float xr[13][256];
    __shared__ float sm[NHEAD][13];
    __shared__ float walpha[NHEAD][13];
    __shared__ float mxs[NHEAD], invs[NHEAD];

    for (int i = tid; i < 13 * 32; i += 256) {
        int r = i >> 5, c8 = (i & 31) * 8;
        int src = (r == 0) ? j : (N_HOPS + j * HOP_LEN + r - 1);
        uint4 u = *(const uint4*)&xb[(size_t)src * 256 + c8];
        float4 lo, hi;
        lo.x = bf2f((unsigned short)(u.x & 0xFFFF)); lo.y = bf2f((unsigned short)(u.x >> 16));
        lo.z = bf2f((unsigned short)(u.y & 0xFFFF)); lo.w = bf2f((unsigned short)(u.y >> 16));
        hi.x = bf2f((unsigned short)(u.z & 0xFFFF)); hi.y = bf2f((unsigned short)(u.z >> 16));
        hi.z = bf2f((unsigned short)(u.w & 0xFFFF)); hi.w = bf2f((unsigned short)(u.w >> 16));
        *(float4*)&xr[r][c8] = lo;
        *(float4*)&xr[r][c8 + 4] = hi;
    }
    if (tid < NHEAD * 13) {
        int h = tid / 13, k = tid % 13;
        int src = (k == 0) ? j : (N_HOPS + j * HOP_LEN + k - 1);
        float ad = bf2f(gb[(size_t)j * GLD + 264 + h]);
        float v = bf2f(gb[(size_t)src * GLD + 256 + h]) + ad;
        sm[h][k] = v > 0.f ? v : 0.2f * v;
    }
    __syncthreads();
    if (tid < NHEAD) {
        int h = tid;
        float mx = sm[h][0];
        for (int k = 1; k < 13; ++k) mx = fmaxf(mx, sm[h][k]);
        float sum = 2.f * expf(sm[h][0] - mx);   // self edge counted twice
        for (int k = 1; k < 13; ++k) sum += expf(sm[h][k] - mx);
        mxs[h] = mx;
        invs[h] = 0.125f / (sum + 1e-16f);
    }
    __syncthreads();
    if (tid < NHEAD * 13) {
        int h = tid / 13, k = tid % 13;
        walpha[h][k] = (k == 0 ? 2.f : 1.f) * expf(sm[h][k] - mxs[h]) * invs[h];
    }
    __syncthreads();
    for (int h = 0; h < NHEAD; ++h) {
        float acc = 0.f;
        #pragma unroll
        for (int r = 0; r < 13; ++r) acc += walpha[h][r] * xr[r][tid];
        z[((size_t)j * NHEAD + h) * 256 + tid] = f2bf(acc);
    }
}

// ---------------------------------------------------------------------------
// bf16 MFMA GEMM (m97 structure): C[M,Nc](ldc) = A @ BT^T + bias
// ---------------------------------------------------------------------------
template <int RELU, int OUT_BF16>
__global__ __launch_bounds__(256) void gemm_bt(
    const unsigned short* __restrict__ A, const unsigned short* __restrict__ BT,
    const float* __restrict__ bias, void* __restrict__ Cout,
    int M, int Nc, int K, int ldc)
{
    __shared__ __align__(16) unsigned short As[128 * 32];
    __shared__ __align__(16) unsigned short Bs[128 * 32];
    const int tid = threadIdx.x;
    const int l = tid & 63;
    const int bm = blockIdx.y * 128, bn = blockIdx.x * 128;
    const int wm = ((tid >> 6) >> 1) * 64, wn = ((tid >> 6) & 1) * 64;

    const int r0 = tid >> 2, ke0 = (tid & 3) * 8;
    const int r1 = (256 + tid) >> 2, ke1 = ((256 + tid) & 3) * 8;
    const unsigned short* ga0 = A + (size_t)(bm + r0) * K + ke0;
    const unsigned short* ga1 = A + (size_t)(bm + r1) * K + ke1;
    const unsigned short* gb0 = BT + (size_t)(bn + r0) * K + ke0;
    const unsigned short* gb1 = BT + (size_t)(bn + r1) * K + ke1;

    f32x4 acc[4][4];
    #pragma unroll
    for (int m = 0; m < 4; ++m)
        #pragma unroll
        for (int n = 0; n < 4; ++n)
            acc[m][n] = (f32x4){0.f, 0.f, 0.f, 0.f};

    const int lrow = l & 15, lk8 = (l >> 4) * 8;

    for (int k0 = 0; k0 < K; k0 += 32) {
        gload16(ga0 + k0, &As[(size_t)tid * 8]);
        gload16(ga1 + k0, &As[(size_t)(256 + tid) * 8]);
        gload16(gb0 + k0, &Bs[(size_t)tid * 8]);
        gload16(gb1 + k0, &Bs[(size_t)(256 + tid) * 8]);
        __syncthreads();
        bf16x8 af[4], bfr[4];
        #pragma unroll
        for (int m = 0; m < 4; ++m)
            af[m] = *(const bf16x8*)&As[(wm + m * 16 + lrow) * 32 + lk8];
        #pragma unroll
        for (int n = 0; n < 4; ++n)
            bfr[n] = *(const bf16x8*)&Bs[(wn + n * 16 + lrow) * 32 + lk8];
        #pragma unroll
        for (int m = 0; m < 4; ++m)
            #pragma unroll
            for (int n = 0; n < 4; ++n)
                acc[m][n] = __builtin_amdgcn_mfma_f32_16x16x32_bf16(
                    af[m], bfr[n], acc[m][n], 0, 0, 0);
        __syncthreads();
    }

    const int orow = (l >> 4) * 4, ocol = l & 15;
    #pragma unroll
    for (int m = 0; m < 4; ++m) {
        int gr = bm + wm + m * 16 + orow;
        #pragma unroll
        for (int n = 0; n < 4; ++n) {
            int gc = bn + wn + n * 16 + ocol;
            float bv = bias[gc];
            #pragma unroll
            for (int r = 0; r < 4; ++r) {
                float v = acc[m][n][r] + bv;
                if (RELU) v = fmaxf(v, 0.f);
                if (OUT_BF16)
                    ((unsigned short*)Cout)[(size_t)(gr + r) * ldc + gc] = f2bf(v);
                else
                    ((float*)Cout)[(size_t)(gr + r) * ldc + gc] = v;
            }
        }
    }
}

// ---------------------------------------------------------------------------
// split-K: partial[z][M][Nc] (bf16) = A[:, z*Ksl:(z+1)*Ksl] @ BT^T
// ---------------------------------------------------------------------------
__global__ __launch_bounds__(256) void gemm_bt_sk(
    const unsigned short* __restrict__ A, const unsigned short* __restrict__ BT,
    unsigned short* __restrict__ Cpart, int M, int Nc, int Ksl, int ldA)
{
    __shared__ __align__(16) unsigned short As[128 * 32];
    __shared__ __align__(16) unsigned short Bs[128 * 32];
    const int tid = threadIdx.x;
    const int l = tid & 63;
    const int bm = blockIdx.y * 128, bn = blockIdx.x * 128;
    const int koff = blockIdx.z * Ksl;
    const int wm = ((tid >> 6) >> 1) * 64, wn = ((tid >> 6) & 1) * 64;

    const int r0 = tid >> 2, ke0 = (tid & 3) * 8;
    const int r1 = (256 + tid) >> 2, ke1 = ((256 + tid) & 3) * 8;
    const unsigned short* ga0 = A + (size_t)(bm + r0) * ldA + koff + ke0;
    const unsigned short* ga1 = A + (size_t)(bm + r1) * ldA + koff + ke1;
    const unsigned short* gb0 = BT + (size_t)(bn + r0) * ldA + koff + ke0;
    const unsigned short* gb1 = BT + (size_t)(bn + r1) * ldA + koff + ke1;

    f32x4 acc[4][4];
    #pragma unroll
    for (int m = 0; m < 4; ++m)
        #pragma unroll
        for (int n = 0; n < 4; ++n)
            acc[m][n] = (f32x4){0.f, 0.f, 0.f, 0.f};

    const int lrow = l & 15, lk8 = (l >> 4) * 8;

    for (int k0 = 0; k0 < Ksl; k0 += 32) {
        gload16(ga0 + k0, &As[(size_t)tid * 8]);
        gload16(ga1 + k0, &As[(size_t)(256 + tid) * 8]);
        gload16(gb0 + k0, &Bs[(size_t)tid * 8]);
        gload16(gb1 + k0, &Bs[(size_t)(256 + tid) * 8]);
        __syncthreads();
        bf16x8 af[4], bfr[4];
        #pragma unroll
        for (int m = 0; m < 4; ++m)
            af[m] = *(const bf16x8*)&As[(wm + m * 16 + lrow) * 32 + lk8];
        #pragma unroll
        for (int n = 0; n < 4; ++n)
            bfr[n] = *(const bf16x8*)&Bs[(wn + n * 16 + lrow) * 32 + lk8];
        #pragma unroll
        for (int m = 0; m < 4; ++m)
            #pragma unroll
            for (int n = 0; n < 4; ++n)
                acc[m][n] = __builtin_amdgcn_mfma_f32_16x16x32_bf16(
                    af[m], bfr[n], acc[m][n], 0, 0, 0);
        __syncthreads();
    }

    unsigned short* Cp = Cpart + (size_t)blockIdx.z * M * Nc;
    const int orow = (l >> 4) * 4, ocol = l & 15;
    #pragma unroll
    for (int m = 0; m < 4; ++m) {
        int gr = bm + wm + m * 16 + orow;
        #pragma unroll
        for (int n = 0; n < 4; ++n) {
            int gc = bn + wn + n * 16 + ocol;
            #pragma unroll
            for (int r = 0; r < 4; ++r)
                Cp[(size_t)(gr + r) * Nc + gc] = f2bf(acc[m][n][r]);
        }
    }
}

// ---------------------------------------------------------------------------
// hop reduce: gbuf[row][col] = bf16( sum_z hopP[z][row][col] + bias[col] )
// ---------------------------------------------------------------------------
__global__ __launch_bounds__(256) void red_hop(
    const unsigned short* __restrict__ P, const float* __restrict__ bias,
    unsigned short* __restrict__ gbuf)
{
    int i = blockIdx.x * 256 + threadIdx.x;       // group of 4 cols
    int row = i >> 6, c4 = (i & 63) * 4;
    float4 s = { 0.f, 0.f, 0.f, 0.f };
    #pragma unroll
    for (int zz = 0; zz < 8; ++zz) {
        ushort4 u = *(const ushort4*)&P[(size_t)zz * N_HOPS * 256 + (size_t)row * 256 + c4];
        s.x += bf2f(u.x); s.y += bf2f(u.y); s.z += bf2f(u.z); s.w += bf2f(u.w);
    }
    float4 bv = *(const float4*)&bias[c4];
    ushort4 o;
    o.x = f2bf(s.x + bv.x); o.y = f2bf(s.y + bv.y);
    o.z = f2bf(s.z + bv.z); o.w = f2bf(s.w + bv.w);
    *(ushort4*)&gbuf[(size_t)row * GLD + c4] = o;
}

// ---------------------------------------------------------------------------
// x1 = LayerNorm(a + b) -> bf16; a bf16 stride GLD, b bf16 stride 256
// ---------------------------------------------------------------------------
__global__ __launch_bounds__(256) void ln_add_bb(
    const unsigned short* __restrict__ a, const unsigned short* __restrict__ b,
    const float* __restrict__ g, const float* __restrict__ be,
    unsigned short* __restrict__ outp)
{
    int wave = threadIdx.x >> 6, lane = threadIdx.x & 63;
    int n = blockIdx.x * 4 + wave;
    ushort4 av = *(const ushort4*)&a[(size_t)n * GLD + lane * 4];
    ushort4 bv = ((const ushort4*)b)[(size_t)n * 64 + lane];
    float v[4];
    v[0] = bf2f(av.x) + bf2f(bv.x); v[1] = bf2f(av.y) + bf2f(bv.y);
    v[2] = bf2f(av.z) + bf2f(bv.z); v[3] = bf2f(av.w) + bf2f(bv.w);
    float s = v[0] + v[1] + v[2] + v[3];
    for (int o = 32; o > 0; o >>= 1) s += __shfl_xor(s, o);
    float mu = s * (1.f / 256.f);
    float q = 0.f;
    #pragma unroll
    for (int i = 0; i < 4; ++i) { float d = v[i] - mu; q += d * d; }
    for (int o = 32; o > 0; o >>= 1) q += __shfl_xor(q, o);
    float rstd = rsqrtf(q * (1.f / 256.f) + 1e-5f);
    int c = lane * 4;
    float4 gv = *(const float4*)&g[c];
    float4 bev = *(const float4*)&be[c];
    ushort4 o4;
    o4.x = f2bf((v[0] - mu) * rstd * gv.x + bev.x);
    o4.y = f2bf((v[1] - mu) * rstd * gv.y + bev.y);
    o4.z = f2bf((v[2] - mu) * rstd * gv.z + bev.z);
    o4.w = f2bf((v[3] - mu) * rstd * gv.w + bev.w);
    ((ushort4*)outp)[(size_t)n * 64 + lane] = o4;
}

// ---------------------------------------------------------------------------
// fused FFN + LN2: out = LN( relu(x1@W1+b1)@W2 + b2 + x1 )
// 512 thr (8 waves), 128-row tile, 16 k-chunks of 64 h-cols, hid never in HBM.
// All LDS operand buffers use granule-XOR swizzle (g ^= row&3) applied at the
// pre-permuted global source (gload_lds writes linearly).
// ---------------------------------------------------------------------------
__global__ __launch_bounds__(512, 2) void fused_ffn(
    const unsigned short* __restrict__ x1b, const unsigned short* __restrict__ W1T,
    const float* __restrict__ b1, const unsigned short* __restrict__ W2T,
    const float* __restrict__ b2, const float* __restrict__ g2,
    const float* __restrict__ be2, float* __restrict__ out)
{
    __shared__ __align__(16) unsigned short sX1[8 * 128 * 32];  // [ks][row][k32] 64K
    __shared__ __align__(16) unsigned short sW1[8 * 64 * 32];   // [ks][hcol][k32] 32K
    __shared__ __align__(16) unsigned short sW2[2 * 256 * 32];  // [k2][fcol][k32] 32K
    __shared__ __align__(16) unsigned short sH[2 * 128 * 32];   // [k2][row][k32] 16K
    __shared__ float lnS[128][4], lnQ[128][4], lnMu[128], lnRs[128];

    const int tid = threadIdx.x, l = tid & 63, wid = tid >> 6;
    const int lrow = l & 15, hi16 = l >> 4;
    const int row0 = blockIdx.x * 128;
    const int wm1 = (wid >> 1) * 32, wn1 = (wid & 1) * 32;   // stage1: 32x32/wave
    const int wm2 = (wid >> 2) * 64, wn2 = (wid & 3) * 64;   // stage2: 64x64/wave

    float b2c[4], gc[4], bc[4];
    #pragma unroll
    for (int n = 0; n < 4; ++n) {
        int col = wn2 + n * 16 + lrow;
        b2c[n] = b2[col]; gc[n] = g2[col]; bc[n] = be2[col];
    }

    // stage x1 tile once (source granule pre-permuted for the XOR swizzle)
    #pragma unroll
    for (int i = 0; i < 8; ++i) {
        int c = i * 512 + tid;
        int s = c >> 9, r = (c >> 2) & 127, q = c & 3;
        int gq = q ^ (r & 3);
        gload16(x1b + (size_t)(row0 + r) * 256 + s * 32 + gq * 8, &sX1[c * 8]);
    }
    // stage W chunk 0
    #pragma unroll
    for (int i = 0; i < 4; ++i) {
        int c = i * 512 + tid;
        int s = c >> 8, hc = (c >> 2) & 63, q = c & 3;
        gload16(W1T + (size_t)hc * 256 + s * 32 + (q ^ (hc & 3)) * 8, &sW1[c * 8]);
    }
    #pragma unroll
    for (int i = 0; i < 4; ++i) {
        int c = i * 512 + tid;
        int k2 = c >> 10, fc = (c >> 2) & 255, q = c & 3;
        gload16(W2T + (size_t)fc * 1024 + k2 * 32 + (q ^ (fc & 3)) * 8, &sW2[c * 8]);
    }
    __syncthreads();

    f32x4 facc[4][4];
    #pragma unroll
    for (int m = 0; m < 4; ++m)
        #pragma unroll
        for (int n = 0; n < 4; ++n)
            facc[m][n] = (f32x4){0.f, 0.f, 0.f, 0.f};

    const int ra = wm1 + lrow, rb = wm1 + 16 + lrow;
    const int rc = wn1 + lrow, rd = wn1 + 16 + lrow;
    const int oa = ((hi16 ^ (ra & 3)) << 3), ob = ((hi16 ^ (rb & 3)) << 3);
    const int oc = ((hi16 ^ (rc & 3)) << 3), od = ((hi16 ^ (rd & 3)) << 3);

    for (int ch = 0; ch < 16; ++ch) {
        // ---- stage1: h[128][64] = relu(x1 @ W1c + b1c)
        f32x4 hacc[2][2];
        #pragma unroll
        for (int m = 0; m < 2; ++m)
            #pragma unroll
            for (int n = 0; n < 2; ++n)
                hacc[m][n] = (f32x4){0.f, 0.f, 0.f, 0.f};
        #pragma unroll
        for (int ks = 0; ks < 8; ++ks) {
            bf16x8 a0 = *(const bf16x8*)&sX1[ks * 4096 + ra * 32 + oa];
            bf16x8 a1 = *(const bf16x8*)&sX1[ks * 4096 + rb * 32 + ob];
            bf16x8 w0 = *(const bf16x8*)&sW1[ks * 2048 + rc * 32 + oc];
            bf16x8 w1 = *(const bf16x8*)&sW1[ks * 2048 + rd * 32 + od];
            hacc[0][0] = __builtin_amdgcn_mfma_f32_16x16x32_bf16(a0, w0, hacc[0][0], 0, 0, 0);
            hacc[0][1] = __builtin_amdgcn_mfma_f32_16x16x32_bf16(a0, w1, hacc[0][1], 0, 0, 0);
            hacc[1][0] = __builtin_amdgcn_mfma_f32_16x16x32_bf16(a1, w0, hacc[1][0], 0, 0, 0);
            hacc[1][1] = __builtin_amdgcn_mfma_f32_16x16x32_bf16(a1, w1, hacc[1][1], 0, 0, 0);
        }
        #pragma unroll
        for (int n = 0; n < 2; ++n) {
            int hcol = wn1 + n * 16 + lrow;
            float bb = b1[ch * 64 + hcol];
            int k2 = hcol >> 5, kk = hcol & 31;
            #pragma unroll
            for (int m = 0; m < 2; ++m) {
                #pragma unroll
                for (int r = 0; r < 4; ++r) {
                    int row = wm1 + m * 16 + hi16 * 4 + r;
                    float v = fmaxf(hacc[m][n][r] + bb, 0.f);
                    sH[k2 * 4096 + row * 32 + ((((kk >> 3) ^ (row & 3)) << 3) | (kk & 7))] = f2bf(v);
                }
            }
        }
        __syncthreads();   // B1: sH ready
        // ---- stage2: ff += h @ W2c
        #pragma unroll
        for (int k2 = 0; k2 < 2; ++k2) {
            bf16x8 a[4];
            #pragma unroll
            for (int m = 0; m < 4; ++m) {
                int r = wm2 + m * 16 + lrow;
                a[m] = *(const bf16x8*)&sH[k2 * 4096 + r * 32 + ((hi16 ^ (r & 3)) << 3)];
            }
            #pragma unroll
            for (int n = 0; n < 4; ++n) {
                int r = wn2 + n * 16 + lrow;
                bf16x8 w = *(const bf16x8*)&sW2[k2 * 8192 + r * 32 + ((hi16 ^ (r & 3)) << 3)];
                #pragma unroll
                for (int m = 0; m < 4; ++m)
                    facc[m][n] = __builtin_amdgcn_mfma_f32_16x16x32_bf16(a[m], w, facc[m][n], 0, 0, 0);
            }
        }
        __syncthreads();   // B2: done reading sW1/sW2/sH
        if (ch < 15) {
            int c2 = ch + 1;
            #pragma unroll
            for (int i = 0; i < 4; ++i) {
                int c = i * 512 + tid;
                int s = c >> 8, hc = (c >> 2) & 63, q = c & 3;
                gload16(W1T + (size_t)(c2 * 64 + hc) * 256 + s * 32 + (q ^ (hc & 3)) * 8, &sW1[c * 8]);
            }
            #pragma unroll
            for (int i = 0; i < 4; ++i) {
                int c = i * 512 + tid;
                int k2 = c >> 10, fc = (c >> 2) & 255, q = c & 3;
                gload16(W2T + (size_t)fc * 1024 + c2 * 64 + k2 * 32 + (q ^ (fc & 3)) * 8, &sW2[c * 8]);
            }
            __syncthreads(); // B3: staging complete
        }
    }

    // ---- epilogue: v = ff + b2 + x1(residual from sX1), then LN2
    #pragma unroll
    for (int m = 0; m < 4; ++m) {
        #pragma unroll
        for (int n = 0; n < 4; ++n) {
            int col = wn2 + n * 16 + lrow;
            int s = col >> 5, kk = col & 31;
            #pragma unroll
            for (int r = 0; r < 4; ++r) {
                int row = wm2 + m * 16 + hi16 * 4 + r;
                float res = bf2f(sX1[s * 4096 + row * 32 +
                                     ((((kk >> 3) ^ (row & 3)) << 3) | (kk & 7))]);
                facc[m][n][r] += b2c[n] + res;
            }
        }
    }
    #pragma unroll
    for (int m = 0; m < 4; ++m) {
        #pragma unroll
        for (int r = 0; r < 4; ++r) {
            float s = 0.f, q = 0.f;
            #pragma unroll
            for (int n = 0; n < 4; ++n) { float v = facc[m][n][r]; s += v; q += v * v; }
            #pragma unroll
            for (int o = 8; o >= 1; o >>= 1) { s += __shfl_xor(s, o); q += __shfl_xor(q, o); }
            if (lrow == 0) {
                int row = wm2 + m * 16 + hi16 * 4 + r;
                lnS[row][wid & 3] = s; lnQ[row][wid & 3] = q;
            }
        }
    }
    __syncthreads();
    if (tid < 128) {
        float s = lnS[tid][0] + lnS[tid][1] + lnS[tid][2] + lnS[tid][3];
        float q = lnQ[tid][0] + lnQ[tid][1] + lnQ[tid][2] + lnQ[tid][3];
        float mu = s * (1.f / 256.f);
        lnMu[tid] = mu;
        lnRs[tid] = rsqrtf(q * (1.f / 256.f) - mu * mu + 1e-5f);
    }
    __syncthreads();
    #pragma unroll
    for (int m = 0; m < 4; ++m) {
        #pragma unroll
        for (int r = 0; r < 4; ++r) {
            int row = wm2 + m * 16 + hi16 * 4 + r;
            float mu = lnMu[row], rs = lnRs[row];
            #pragma unroll
            for (int n = 0; n < 4; ++n) {
                int col = wn2 + n * 16 + lrow;
                out[(size_t)(row0 + row) * 256 + col] =
                    (facc[m][n][r] - mu) * rs * gc[n] + bc[n];
            }
        }
    }
}

// ---------------------------------------------------------------------------
extern "C" void kernel_launch(void* const* d_in, const int* in_sizes, int n_in,
                              void* d_out, int out_size, void* d_ws, size_t ws_size,
                              hipStream_t stream)
{
    const float* x       = (const float*)d_in[0];
    const float* gat_W   = (const float*)d_in[2];
    const float* att_src = (const float*)d_in[3];
    const float* att_dst = (const float*)d_in[4];
    const float* gat_b   = (const float*)d_in[5];
    const float* W1      = (const float*)d_in[6];
    const float* b1      = (const float*)d_in[7];
    const float* W2      = (const float*)d_in[8];
    const float* b2      = (const float*)d_in[9];
    const float* ln1_g   = (const float*)d_in[10];
    const float* ln1_b   = (const float*)d_in[11];
    const float* ln2_g   = (const float*)d_in[12];
    const float* ln2_b   = (const float*)d_in[13];
    float* out = (float*)d_out;

    char* p = (char*)d_ws;
    auto carve = [&p](size_t bytes) { char* r = p; p += (bytes + 255) & ~(size_t)255; return r; };
    unsigned short* gbuf = (unsigned short*)carve((size_t)N_TOT * GLD * 2);  // bf16 [N][384]
    unsigned short* x1b  = (unsigned short*)carve((size_t)N_TOT * 256 * 2);  // xb -> x1
    unsigned short* z    = (unsigned short*)carve((size_t)N_HOPS * 2048 * 2);
    unsigned short* hopP = (unsigned short*)carve((size_t)8 * N_HOPS * 256 * 2);
    unsigned short* BcT  = (unsigned short*)carve((size_t)GLD * 256 * 2);
    unsigned short* B2T  = (unsigned short*)carve((size_t)2048 * 256 * 2);
    unsigned short* W1T  = (unsigned short*)carve((size_t)FFD * 256 * 2);
    unsigned short* W2T  = (unsigned short*)carve((size_t)256 * FFD * 2);
    float*          bias384 = (float*)carve(GLD * 4);

    // 0. small prep
    hipMemsetAsync(BcT + 272 * 256, 0, (size_t)(GLD - 272) * 256 * 2, stream);
    hipMemcpyAsync(bias384, gat_b, 256 * 4, hipMemcpyDeviceToDevice, stream);
    hipMemsetAsync(bias384 + 256, 0, (GLD - 256) * 4, stream);
    // 1. weight prep + transposes
    hipLaunchKernelGGL(prep_w, dim3(256), dim3(256), 0, stream,
                       gat_W, att_src, att_dst, BcT);
    hipLaunchKernelGGL(tconv, dim3(8, 8, 8), dim3(32, 8), 0, stream,
                       gat_W, B2T, 2048, 2048, 256, 256);
    hipLaunchKernelGGL(tconv, dim3(32, 8, 1), dim3(32, 8), 0, stream,
                       W1, W1T, 1024, 256, 0, 0);
    hipLaunchKernelGGL(tconv, dim3(8, 32, 1), dim3(32, 8), 0, stream,
                       W2, W2T, 256, 1024, 0, 0);
    // 2. x -> bf16
    hipLaunchKernelGGL(cvt_bf16, dim3(N_TOT * 256 / 4 / 256), dim3(256), 0, stream,
                       x, x1b, N_TOT * 256 / 4);
    // 3. combined GEMM: gbuf[n][0:256]=x@Wm+gat_b (bf16), [256:272]=attn logits
    hipLaunchKernelGGL((gemm_bt<0, 1>), dim3(GLD / 128, N_TOT / 128), dim3(256), 0, stream,
                       x1b, BcT, bias384, gbuf, N_TOT, GLD, 256, GLD);
    // 4. hop softmax + aggregation
    hipLaunchKernelGGL(hop_z, dim3(N_HOPS), dim3(256), 0, stream,
                       x1b, gbuf, z);
    // 5. g_hop = z @ B2 + bias (split-K=8 partials, then reduce)
    hipLaunchKernelGGL(gemm_bt_sk, dim3(2, N_HOPS / 128, 8), dim3(256), 0, stream,
                       z, B2T, hopP, N_HOPS, 256, 256, 2048);
    hipLaunchKernelGGL(red_hop, dim3(N_HOPS * 64 / 256), dim3(256), 0, stream,
                       hopP, gat_b, gbuf);
    // 6. x1 = LN(g + x) -> bf16 (in place over x1b)
    hipLaunchKernelGGL(ln_add_bb, dim3(N_TOT / 4), dim3(256), 0, stream,
                       gbuf, x1b, ln1_g, ln1_b, x1b);
    // 7. fused FFN1+FFN2+LN2 -> out (fp32), hid stays on-chip
    hipLaunchKernelGGL(fused_ffn, dim3(N_TOT / 128), dim3(512), 0, stream,
                       x1b, W1T, b1, W2T, b2, ln2_g, ln2_b, out);
    (void)in_sizes; (void)n_in; (void)out_size; (void)ws_size;
}

// Round 6
// 213.028 us; speedup vs baseline: 7.8685x; 1.0934x over previous
//
#include <hip/hip_runtime.h>
#include <cstdint>
#include <cstddef>

#define N_TOT   53248
#define N_HOPS  4096
#define HOP_LEN 12
#define NHEAD   8
#define FFD     1024
#define GLD     384     // gbuf leading dim: 256 (g_out) + 8 a_s + 8 a_d + pad

typedef __bf16 bf16x8 __attribute__((ext_vector_type(8)));
typedef float f32x4 __attribute__((ext_vector_type(4)));
typedef float f32x16 __attribute__((ext_vector_type(16)));

__device__ __forceinline__ unsigned short f2bf(float f) {
    unsigned int u = __float_as_uint(f);
    u += 0x7FFFu + ((u >> 16) & 1u);
    return (unsigned short)(u >> 16);
}
__device__ __forceinline__ float bf2f(unsigned short b) {
    return __uint_as_float((unsigned int)b << 16);
}
__device__ __forceinline__ void gload16(const void* g, void* l) {
    __builtin_amdgcn_global_load_lds(
        (const __attribute__((address_space(1))) void*)g,
        (__attribute__((address_space(3))) void*)l, 16, 0, 0);
}

// ---------------------------------------------------------------------------
// prep: BcT rows 0-255 = Wm^T (bf16), rows 256-263 = wsrc^T, 264-271 = wdst^T
// ---------------------------------------------------------------------------
__global__ __launch_bounds__(256) void prep_w(
    const float* __restrict__ W, const float* __restrict__ att_s,
    const float* __restrict__ att_d, unsigned short* __restrict__ BcT)
{
    int d = blockIdx.x, c = threadIdx.x;
    int wave = c >> 6;
    __shared__ float ps4[4], pd4[4];
    float wm = 0.f;
    for (int h = 0; h < NHEAD; ++h) {
        float w = W[d * 2048 + h * 256 + c];
        wm += w;
        float ps = w * att_s[h * 256 + c];
        float pd = w * att_d[h * 256 + c];
        for (int o = 32; o > 0; o >>= 1) {
            ps += __shfl_xor(ps, o);
            pd += __shfl_xor(pd, o);
        }
        if ((c & 63) == 0) { ps4[wave] = ps; pd4[wave] = pd; }
        __syncthreads();
        if (c == 0) BcT[(256 + h) * 256 + d] = f2bf(ps4[0] + ps4[1] + ps4[2] + ps4[3]);
        if (c == 1) BcT[(264 + h) * 256 + d] = f2bf(pd4[0] + pd4[1] + pd4[2] + pd4[3]);
        __syncthreads();
    }
    BcT[c * 256 + d] = f2bf(wm * 0.125f);
}

// ---------------------------------------------------------------------------
__global__ __launch_bounds__(256) void tconv(
    const float* __restrict__ in, unsigned short* __restrict__ out,
    int IS, int OS, int in_zoff, int out_zoff)
{
    __shared__ float t[32][33];
    in  += (size_t)blockIdx.z * in_zoff;
    out += (size_t)blockIdx.z * out_zoff;
    int tx = threadIdx.x, ty = threadIdx.y;
    int c0 = blockIdx.x * 32, r0 = blockIdx.y * 32;
    #pragma unroll
    for (int k = 0; k < 4; ++k)
        t[ty + 8 * k][tx] = in[(size_t)(r0 + ty + 8 * k) * IS + c0 + tx];
    __syncthreads();
    #pragma unroll
    for (int k = 0; k < 4; ++k)
        out[(size_t)(c0 + ty + 8 * k) * OS + r0 + tx] = f2bf(t[tx][ty + 8 * k]);
}

// ---------------------------------------------------------------------------
__global__ __launch_bounds__(256) void cvt_bf16(
    const float* __restrict__ in, unsigned short* __restrict__ out, int n4)
{
    int i = blockIdx.x * 256 + threadIdx.x;
    if (i >= n4) return;
    float4 v = ((const float4*)in)[i];
    ushort4 o;
    o.x = f2bf(v.x); o.y = f2bf(v.y); o.z = f2bf(v.z); o.w = f2bf(v.w);
    ((ushort4*)out)[i] = o;
}

// ---------------------------------------------------------------------------
// hop softmax + weighted x aggregation (logits from bf16 gbuf cols 256..271)
// ---------------------------------------------------------------------------
__global__ __launch_bounds__(256) void hop_z(
    const unsigned short* __restrict__ xb, const unsigned short* __restrict__ gb,
    unsigned short* __restrict__ z)
{
    int j = blockIdx.x, tid = threadIdx.x;
    __shared__ float xr[13][256];
    __shared__ float sm[NHEAD][13];
    __shared__ float walpha[NHEAD][13];
    __shared__ float mxs[NHEAD], invs[NHEAD];

    for (int i = tid; i < 13 * 32; i += 256) {
        int r = i >> 5, c8 = (i & 31) * 8;
        int src = (r == 0) ? j : (N_HOPS + j * HOP_LEN + r - 1);
        uint4 u = *(const uint4*)&xb[(size_t)src * 256 + c8];
        float4 lo, hi;
        lo.x = bf2f((unsigned short)(u.x & 0xFFFF)); lo.y = bf2f((unsigned short)(u.x >> 16));
        lo.z = bf2f((unsigned short)(u.y & 0xFFFF)); lo.w = bf2f((unsigned short)(u.y >> 16));
        hi.x = bf2f((unsigned short)(u.z & 0xFFFF)); hi.y = bf2f((unsigned short)(u.z >> 16));
        hi.z = bf2f((unsigned short)(u.w & 0xFFFF)); hi.w = bf2f((unsigned short)(u.w >> 16));
        *(float4*)&xr[r][c8] = lo;
        *(float4*)&xr[r][c8 + 4] = hi;
    }
    if (tid < NHEAD * 13) {
        int h = tid / 13, k = tid % 13;
        int src = (k == 0) ? j : (N_HOPS + j * HOP_LEN + k - 1);
        float ad = bf2f(gb[(size_t)j * GLD + 264 + h]);
        float v = bf2f(gb[(size_t)src * GLD + 256 + h]) + ad;
        sm[h][k] = v > 0.f ? v : 0.2f * v;
    }
    __syncthreads();
    if (tid < NHEAD) {
        int h = tid;
        float mx = sm[h][0];
        for (int k = 1; k < 13; ++k) mx = fmaxf(mx, sm[h][k]);
        float sum = 2.f * expf(sm[h][0] - mx);   // self edge counted twice
        for (int k = 1; k < 13; ++k) sum += expf(sm[h][k] - mx);
        mxs[h] = mx;
        invs[h] = 0.125f / (sum + 1e-16f);
    }
    __syncthreads();
    if (tid < NHEAD * 13) {
        int h = tid / 13, k = tid % 13;
        walpha[h][k] = (k == 0 ? 2.f : 1.f) * expf(sm[h][k] - mxs[h]) * invs[h];
    }
    __syncthreads();
    for (int h = 0; h < NHEAD; ++h) {
        float acc = 0.f;
        #pragma unroll
        for (int r = 0; r < 13; ++r) acc += walpha[h][r] * xr[r][tid];
        z[((size_t)j * NHEAD + h) * 256 + tid] = f2bf(acc);
    }
}

// ---------------------------------------------------------------------------
// bf16 MFMA GEMM (m97 structure): C[M,Nc](ldc) = A @ BT^T + bias
// ---------------------------------------------------------------------------
template <int RELU, int OUT_BF16>
__global__ __launch_bounds__(256) void gemm_bt(
    const unsigned short* __restrict__ A, const unsigned short* __restrict__ BT,
    const float* __restrict__ bias, void* __restrict__ Cout,
    int M, int Nc, int K, int ldc)
{
    __shared__ __align__(16) unsigned short As[128 * 32];
    __shared__ __align__(16) unsigned short Bs[128 * 32];
    const int tid = threadIdx.x;
    const int l = tid & 63;
    const int bm = blockIdx.y * 128, bn = blockIdx.x * 128;
    const int wm = ((tid >> 6) >> 1) * 64, wn = ((tid >> 6) & 1) * 64;

    const int r0 = tid >> 2, ke0 = (tid & 3) * 8;
    const int r1 = (256 + tid) >> 2, ke1 = ((256 + tid) & 3) * 8;
    const unsigned short* ga0 = A + (size_t)(bm + r0) * K + ke0;
    const unsigned short* ga1 = A + (size_t)(bm + r1) * K + ke1;
    const unsigned short* gb0 = BT + (size_t)(bn + r0) * K + ke0;
    const unsigned short* gb1 = BT + (size_t)(bn + r1) * K + ke1;

    f32x4 acc[4][4];
    #pragma unroll
    for (int m = 0; m < 4; ++m)
        #pragma unroll
        for (int n = 0; n < 4; ++n)
            acc[m][n] = (f32x4){0.f, 0.f, 0.f, 0.f};

    const int lrow = l & 15, lk8 = (l >> 4) * 8;

    for (int k0 = 0; k0 < K; k0 += 32) {
        gload16(ga0 + k0, &As[(size_t)tid * 8]);
        gload16(ga1 + k0, &As[(size_t)(256 + tid) * 8]);
        gload16(gb0 + k0, &Bs[(size_t)tid * 8]);
        gload16(gb1 + k0, &Bs[(size_t)(256 + tid) * 8]);
        __syncthreads();
        bf16x8 af[4], bfr[4];
        #pragma unroll
        for (int m = 0; m < 4; ++m)
            af[m] = *(const bf16x8*)&As[(wm + m * 16 + lrow) * 32 + lk8];
        #pragma unroll
        for (int n = 0; n < 4; ++n)
            bfr[n] = *(const bf16x8*)&Bs[(wn + n * 16 + lrow) * 32 + lk8];
        #pragma unroll
        for (int m = 0; m < 4; ++m)
            #pragma unroll
            for (int n = 0; n < 4; ++n)
                acc[m][n] = __builtin_amdgcn_mfma_f32_16x16x32_bf16(
                    af[m], bfr[n], acc[m][n], 0, 0, 0);
        __syncthreads();
    }

    const int orow = (l >> 4) * 4, ocol = l & 15;
    #pragma unroll
    for (int m = 0; m < 4; ++m) {
        int gr = bm + wm + m * 16 + orow;
        #pragma unroll
        for (int n = 0; n < 4; ++n) {
            int gc = bn + wn + n * 16 + ocol;
            float bv = bias[gc];
            #pragma unroll
            for (int r = 0; r < 4; ++r) {
                float v = acc[m][n][r] + bv;
                if (RELU) v = fmaxf(v, 0.f);
                if (OUT_BF16)
                    ((unsigned short*)Cout)[(size_t)(gr + r) * ldc + gc] = f2bf(v);
                else
                    ((float*)Cout)[(size_t)(gr + r) * ldc + gc] = v;
            }
        }
    }
}

// ---------------------------------------------------------------------------
// split-K: partial[z][M][Nc] (bf16) = A[:, z*Ksl:(z+1)*Ksl] @ BT^T
// ---------------------------------------------------------------------------
__global__ __launch_bounds__(256) void gemm_bt_sk(
    const unsigned short* __restrict__ A, const unsigned short* __restrict__ BT,
    unsigned short* __restrict__ Cpart, int M, int Nc, int Ksl, int ldA)
{
    __shared__ __align__(16) unsigned short As[128 * 32];
    __shared__ __align__(16) unsigned short Bs[128 * 32];
    const int tid = threadIdx.x;
    const int l = tid & 63;
    const int bm = blockIdx.y * 128, bn = blockIdx.x * 128;
    const int koff = blockIdx.z * Ksl;
    const int wm = ((tid >> 6) >> 1) * 64, wn = ((tid >> 6) & 1) * 64;

    const int r0 = tid >> 2, ke0 = (tid & 3) * 8;
    const int r1 = (256 + tid) >> 2, ke1 = ((256 + tid) & 3) * 8;
    const unsigned short* ga0 = A + (size_t)(bm + r0) * ldA + koff + ke0;
    const unsigned short* ga1 = A + (size_t)(bm + r1) * ldA + koff + ke1;
    const unsigned short* gb0 = BT + (size_t)(bn + r0) * ldA + koff + ke0;
    const unsigned short* gb1 = BT + (size_t)(bn + r1) * ldA + koff + ke1;

    f32x4 acc[4][4];
    #pragma unroll
    for (int m = 0; m < 4; ++m)
        #pragma unroll
        for (int n = 0; n < 4; ++n)
            acc[m][n] = (f32x4){0.f, 0.f, 0.f, 0.f};

    const int lrow = l & 15, lk8 = (l >> 4) * 8;

    for (int k0 = 0; k0 < Ksl; k0 += 32) {
        gload16(ga0 + k0, &As[(size_t)tid * 8]);
        gload16(ga1 + k0, &As[(size_t)(256 + tid) * 8]);
        gload16(gb0 + k0, &Bs[(size_t)tid * 8]);
        gload16(gb1 + k0, &Bs[(size_t)(256 + tid) * 8]);
        __syncthreads();
        bf16x8 af[4], bfr[4];
        #pragma unroll
        for (int m = 0; m < 4; ++m)
            af[m] = *(const bf16x8*)&As[(wm + m * 16 + lrow) * 32 + lk8];
        #pragma unroll
        for (int n = 0; n < 4; ++n)
            bfr[n] = *(const bf16x8*)&Bs[(wn + n * 16 + lrow) * 32 + lk8];
        #pragma unroll
        for (int m = 0; m < 4; ++m)
            #pragma unroll
            for (int n = 0; n < 4; ++n)
                acc[m][n] = __builtin_amdgcn_mfma_f32_16x16x32_bf16(
                    af[m], bfr[n], acc[m][n], 0, 0, 0);
        __syncthreads();
    }

    unsigned short* Cp = Cpart + (size_t)blockIdx.z * M * Nc;
    const int orow = (l >> 4) * 4, ocol = l & 15;
    #pragma unroll
    for (int m = 0; m < 4; ++m) {
        int gr = bm + wm + m * 16 + orow;
        #pragma unroll
        for (int n = 0; n < 4; ++n) {
            int gc = bn + wn + n * 16 + ocol;
            #pragma unroll
            for (int r = 0; r < 4; ++r)
                Cp[(size_t)(gr + r) * Nc + gc] = f2bf(acc[m][n][r]);
        }
    }
}

// ---------------------------------------------------------------------------
// hop reduce: gbuf[row][col] = bf16( sum_z hopP[z][row][col] + bias[col] )
// ---------------------------------------------------------------------------
__global__ __launch_bounds__(256) void red_hop(
    const unsigned short* __restrict__ P, const float* __restrict__ bias,
    unsigned short* __restrict__ gbuf)
{
    int i = blockIdx.x * 256 + threadIdx.x;       // group of 4 cols
    int row = i >> 6, c4 = (i & 63) * 4;
    float4 s = { 0.f, 0.f, 0.f, 0.f };
    #pragma unroll
    for (int zz = 0; zz < 8; ++zz) {
        ushort4 u = *(const ushort4*)&P[(size_t)zz * N_HOPS * 256 + (size_t)row * 256 + c4];
        s.x += bf2f(u.x); s.y += bf2f(u.y); s.z += bf2f(u.z); s.w += bf2f(u.w);
    }
    float4 bv = *(const float4*)&bias[c4];
    ushort4 o;
    o.x = f2bf(s.x + bv.x); o.y = f2bf(s.y + bv.y);
    o.z = f2bf(s.z + bv.z); o.w = f2bf(s.w + bv.w);
    *(ushort4*)&gbuf[(size_t)row * GLD + c4] = o;
}

// ---------------------------------------------------------------------------
// x1 = LayerNorm(a + b) -> bf16; a bf16 stride GLD, b bf16 stride 256
// ---------------------------------------------------------------------------
__global__ __launch_bounds__(256) void ln_add_bb(
    const unsigned short* __restrict__ a, const unsigned short* __restrict__ b,
    const float* __restrict__ g, const float* __restrict__ be,
    unsigned short* __restrict__ outp)
{
    int wave = threadIdx.x >> 6, lane = threadIdx.x & 63;
    int n = blockIdx.x * 4 + wave;
    ushort4 av = *(const ushort4*)&a[(size_t)n * GLD + lane * 4];
    ushort4 bv = ((const ushort4*)b)[(size_t)n * 64 + lane];
    float v[4];
    v[0] = bf2f(av.x) + bf2f(bv.x); v[1] = bf2f(av.y) + bf2f(bv.y);
    v[2] = bf2f(av.z) + bf2f(bv.z); v[3] = bf2f(av.w) + bf2f(bv.w);
    float s = v[0] + v[1] + v[2] + v[3];
    for (int o = 32; o > 0; o >>= 1) s += __shfl_xor(s, o);
    float mu = s * (1.f / 256.f);
    float q = 0.f;
    #pragma unroll
    for (int i = 0; i < 4; ++i) { float d = v[i] - mu; q += d * d; }
    for (int o = 32; o > 0; o >>= 1) q += __shfl_xor(q, o);
    float rstd = rsqrtf(q * (1.f / 256.f) + 1e-5f);
    int c = lane * 4;
    float4 gv = *(const float4*)&g[c];
    float4 bev = *(const float4*)&be[c];
    ushort4 o4;
    o4.x = f2bf((v[0] - mu) * rstd * gv.x + bev.x);
    o4.y = f2bf((v[1] - mu) * rstd * gv.y + bev.y);
    o4.z = f2bf((v[2] - mu) * rstd * gv.z + bev.z);
    o4.w = f2bf((v[3] - mu) * rstd * gv.w + bev.w);
    ((ushort4*)outp)[(size_t)n * 64 + lane] = o4;
}

// ---------------------------------------------------------------------------
// fused FFN + LN2 v2: out = LN( relu(x1@W1+b1)@W2 + b2 + x1 )
// 256 thr / 4 waves / 64-row block. 32x32x16 MFMA. x1 in registers.
// 16 chunks of 64 hcols; sW1/sW2 staged via global_load_lds w/ XOR-swizzled
// source (rule #21); sH padded rows (144B). Two __syncthreads per chunk;
// W prefetch issued right after the barrier that frees each buffer.
// LDS: sW1 32K | sW2 32K | sH 9K | sB1 4K = 77K -> 2 blocks/CU.
// ---------------------------------------------------------------------------
__global__ __launch_bounds__(256, 2) void fused_ffn(
    const unsigned short* __restrict__ x1b, const unsigned short* __restrict__ W1T,
    const float* __restrict__ b1, const unsigned short* __restrict__ W2T,
    const float* __restrict__ b2, const float* __restrict__ g2,
    const float* __restrict__ be2, float* __restrict__ out)
{
    __shared__ __align__(16) char smem[78848];
    unsigned short* sW1u = (unsigned short*)smem;            // [64 hc][256k] swz
    unsigned short* sW2u = (unsigned short*)(smem + 32768);  // [256 fc][64k] swz
    unsigned short* sHu  = (unsigned short*)(smem + 65536);  // [64 r][72] (pad)
    float*          sB1  = (float*)(smem + 74752);           // [1024]

    const int tid = threadIdx.x, l = tid & 63, w = tid >> 6;
    const int l31 = l & 31, h1 = l >> 5;
    const int row0 = blockIdx.x * 64;
    const int rh  = w >> 1;            // stage1 row half (0/1)
    const int ch1 = (w & 1) * 32;      // stage1 hcol half within chunk
    const int hc  = ch1 + l31;         // stage1 hcol in chunk (0..63)

    // ---- prologue: stage chunk-0 W1/W2 (pre-swizzled source), b1 -> LDS
    #pragma unroll
    for (int i = 0; i < 8; ++i) {
        int c = i * 256 + tid;                        // sW1 granule
        int r = c >> 5, s = c & 31;
        gload16(W1T + (size_t)r * 256 + ((s ^ (r & 7)) * 8), sW1u + c * 8);
    }
    #pragma unroll
    for (int i = 0; i < 8; ++i) {
        int c = i * 256 + tid;                        // sW2 granule
        int r = c >> 3, s = c & 7;
        gload16(W2T + (size_t)r * 1024 + ((s ^ (r & 7)) * 8), sW2u + c * 8);
    }
    {
        float4 bv = ((const float4*)b1)[tid];
        *(float4*)&sB1[tid * 4] = bv;
    }
    // x1 rows of this wave -> registers (A-fragments, k = ks*16 + h1*8)
    bf16x8 a[16];
    {
        const unsigned short* xr = x1b + (size_t)(row0 + rh * 32 + l31) * 256 + h1 * 8;
        #pragma unroll
        for (int ks = 0; ks < 16; ++ks)
            a[ks] = *(const bf16x8*)(xr + ks * 16);
    }
    f32x16 facc[2][2];
    #pragma unroll
    for (int m = 0; m < 2; ++m)
        #pragma unroll
        for (int n = 0; n < 2; ++n)
            facc[m][n] = (f32x16)(0.f);
    __syncthreads();   // W(0), b1 landed & visible

    for (int ch = 0; ch < 16; ++ch) {
        // ---- stage1: h[64][64] quad; this wave: rows rh*32+[0,32), hcols hc
        f32x16 hA = (f32x16)(0.f), hB = (f32x16)(0.f);
        #pragma unroll
        for (int ks = 0; ks < 16; ks += 2) {
            bf16x8 w0 = *(const bf16x8*)&sW1u[hc * 256 + (((2 * ks + h1) ^ (hc & 7)) * 8)];
            bf16x8 w1 = *(const bf16x8*)&sW1u[hc * 256 + (((2 * ks + 2 + h1) ^ (hc & 7)) * 8)];
            hA = __builtin_amdgcn_mfma_f32_32x32x16_bf16(a[ks], w0, hA, 0, 0, 0);
            hB = __builtin_amdgcn_mfma_f32_32x32x16_bf16(a[ks + 1], w1, hB, 0, 0, 0);
        }
        float b1v = sB1[ch * 64 + hc];
        #pragma unroll
        for (int reg = 0; reg < 16; ++reg) {
            int r2 = rh * 32 + (reg & 3) + 8 * (reg >> 2) + 4 * h1;
            float v = fmaxf(hA[reg] + hB[reg] + b1v, 0.f);
            sHu[r2 * 72 + hc] = f2bf(v);
        }
        __syncthreads();                       // alpha: sH visible, sW1 free
        if (ch < 15) {
            #pragma unroll
            for (int i = 0; i < 8; ++i) {
                int c = i * 256 + tid;
                int r = c >> 5, s = c & 31;
                gload16(W1T + (size_t)((ch + 1) * 64 + r) * 256 + ((s ^ (r & 7)) * 8),
                        sW1u + c * 8);
            }
        }
        // ---- stage2: facc += h @ W2chunk ; wave: 64 rows x 64 fcols
        #pragma unroll
        for (int ks = 0; ks < 4; ++ks) {
            bf16x8 am[2], bn[2];
            #pragma unroll
            for (int m = 0; m < 2; ++m)
                am[m] = *(const bf16x8*)&sHu[(m * 32 + l31) * 72 + (2 * ks + h1) * 8];
            #pragma unroll
            for (int n = 0; n < 2; ++n) {
                int fc = w * 64 + n * 32 + l31;
                bn[n] = *(const bf16x8*)&sW2u[fc * 64 + (((2 * ks + h1) ^ (fc & 7)) * 8)];
            }
            #pragma unroll
            for (int m = 0; m < 2; ++m)
                #pragma unroll
                for (int n = 0; n < 2; ++n)
                    facc[m][n] = __builtin_amdgcn_mfma_f32_32x32x16_bf16(
                        am[m], bn[n], facc[m][n], 0, 0, 0);
        }
        __syncthreads();                       // beta: sW2 free, sH free
        if (ch < 15) {
            #pragma unroll
            for (int i = 0; i < 8; ++i) {
                int c = i * 256 + tid;
                int r = c >> 3, s = c & 7;
                gload16(W2T + (size_t)r * 1024 + (ch + 1) * 64 + ((s ^ (r & 7)) * 8),
                        sW2u + c * 8);
            }
        }
    }

    // ---- epilogue: residual + b2, LN2, fp32 out
    float b2c[2], g2c[2], be2c[2];
    #pragma unroll
    for (int n = 0; n < 2; ++n) {
        int fc = w * 64 + n * 32 + l31;
        b2c[n] = b2[fc]; g2c[n] = g2[fc]; be2c[n] = be2[fc];
    }
    // share x1 regs via dead sW1 region: [64 rows][256 k], XOR-swizzled
    if ((w & 1) == 0) {
        int r = rh * 32 + l31;
        #pragma unroll
        for (int ks = 0; ks < 16; ++ks)
            *(bf16x8*)&sW1u[r * 256 + (((2 * ks + h1) ^ (r & 7)) * 8)] = a[ks];
    }
    __syncthreads();
    #pragma unroll
    for (int m = 0; m < 2; ++m)
        #pragma unroll
        for (int n = 0; n < 2; ++n)
            #pragma unroll
            for (int reg = 0; reg < 16; ++reg) {
                int r2 = m * 32 + (reg & 3) + 8 * (reg >> 2) + 4 * h1;
                int fc = w * 64 + n * 32 + l31;
                float res = bf2f(sW1u[r2 * 256 + ((((fc >> 3) ^ (r2 & 7)) * 8) | (fc & 7))]);
                facc[m][n][reg] += b2c[n] + res;
            }
    // LN stats: per-(m,reg) reduce over 32 fcol-lanes, cross-wave via LDS
    float* lnS = (float*)sW2u;          // [64][4]
    float* lnQ = lnS + 256;             // [64][4]
    float* lnM = lnQ + 256;             // [64]
    float* lnR = lnM + 64;              // [64]
    #pragma unroll
    for (int m = 0; m < 2; ++m)
        #pragma unroll
        for (int reg = 0; reg < 16; ++reg) {
            float s = facc[m][0][reg] + facc[m][1][reg];
            float q = facc[m][0][reg] * facc[m][0][reg]
                    + facc[m][1][reg] * facc[m][1][reg];
            #pragma unroll
            for (int o = 16; o >= 1; o >>= 1) {
                s += __shfl_xor(s, o);
                q += __shfl_xor(q, o);
            }
            if (l31 == 0) {
                int r2 = m * 32 + (reg & 3) + 8 * (reg >> 2) + 4 * h1;
                lnS[r2 * 4 + w] = s;
                lnQ[r2 * 4 + w] = q;
            }
        }
    __syncthreads();
    if (tid < 64) {
        float s = lnS[tid * 4] + lnS[tid * 4 + 1] + lnS[tid * 4 + 2] + lnS[tid * 4 + 3];
        float q = lnQ[tid * 4] + lnQ[tid * 4 + 1] + lnQ[tid * 4 + 2] + lnQ[tid * 4 + 3];
        float mu = s * (1.f / 256.f);
        lnM[tid] = mu;
        lnR[tid] = rsqrtf(q * (1.f / 256.f) - mu * mu + 1e-5f);
    }
    __syncthreads();
    #pragma unroll
    for (int m = 0; m < 2; ++m)
        #pragma unroll
        for (int reg = 0; reg < 16; ++reg) {
            int r2 = m * 32 + (reg & 3) + 8 * (reg >> 2) + 4 * h1;
            float mu = lnM[r2], rs = lnR[r2];
            #pragma unroll
            for (int n = 0; n < 2; ++n) {
                int fc = w * 64 + n * 32 + l31;
                out[(size_t)(row0 + r2) * 256 + fc] =
                    (facc[m][n][reg] - mu) * rs * g2c[n] + be2c[n];
            }
        }
}

// ---------------------------------------------------------------------------
extern "C" void kernel_launch(void* const* d_in, const int* in_sizes, int n_in,
                              void* d_out, int out_size, void* d_ws, size_t ws_size,
                              hipStream_t stream)
{
    const float* x       = (const float*)d_in[0];
    const float* gat_W   = (const float*)d_in[2];
    const float* att_src = (const float*)d_in[3];
    const float* att_dst = (const float*)d_in[4];
    const float* gat_b   = (const float*)d_in[5];
    const float* W1      = (const float*)d_in[6];
    const float* b1      = (const float*)d_in[7];
    const float* W2      = (const float*)d_in[8];
    const float* b2      = (const float*)d_in[9];
    const float* ln1_g   = (const float*)d_in[10];
    const float* ln1_b   = (const float*)d_in[11];
    const float* ln2_g   = (const float*)d_in[12];
    const float* ln2_b   = (const float*)d_in[13];
    float* out = (float*)d_out;

    char* p = (char*)d_ws;
    auto carve = [&p](size_t bytes) { char* r = p; p += (bytes + 255) & ~(size_t)255; return r; };
    unsigned short* gbuf = (unsigned short*)carve((size_t)N_TOT * GLD * 2);  // bf16 [N][384]
    unsigned short* x1b  = (unsigned short*)carve((size_t)N_TOT * 256 * 2);  // xb -> x1
    unsigned short* z    = (unsigned short*)carve((size_t)N_HOPS * 2048 * 2);
    unsigned short* hopP = (unsigned short*)carve((size_t)8 * N_HOPS * 256 * 2);
    unsigned short* BcT  = (unsigned short*)carve((size_t)GLD * 256 * 2);
    unsigned short* B2T  = (unsigned short*)carve((size_t)2048 * 256 * 2);
    unsigned short* W1T  = (unsigned short*)carve((size_t)FFD * 256 * 2);
    unsigned short* W2T  = (unsigned short*)carve((size_t)256 * FFD * 2);
    float*          bias384 = (float*)carve(GLD * 4);

    // 0. small prep
    hipMemsetAsync(BcT + 272 * 256, 0, (size_t)(GLD - 272) * 256 * 2, stream);
    hipMemcpyAsync(bias384, gat_b, 256 * 4, hipMemcpyDeviceToDevice, stream);
    hipMemsetAsync(bias384 + 256, 0, (GLD - 256) * 4, stream);
    // 1. weight prep + transposes
    hipLaunchKernelGGL(prep_w, dim3(256), dim3(256), 0, stream,
                       gat_W, att_src, att_dst, BcT);
    hipLaunchKernelGGL(tconv, dim3(8, 8, 8), dim3(32, 8), 0, stream,
                       gat_W, B2T, 2048, 2048, 256, 256);
    hipLaunchKernelGGL(tconv, dim3(32, 8, 1), dim3(32, 8), 0, stream,
                       W1, W1T, 1024, 256, 0, 0);
    hipLaunchKernelGGL(tconv, dim3(8, 32, 1), dim3(32, 8), 0, stream,
                       W2, W2T, 256, 1024, 0, 0);
    // 2. x -> bf16
    hipLaunchKernelGGL(cvt_bf16, dim3(N_TOT * 256 / 4 / 256), dim3(256), 0, stream,
                       x, x1b, N_TOT * 256 / 4);
    // 3. combined GEMM: gbuf[n][0:256]=x@Wm+gat_b (bf16), [256:272]=attn logits
    hipLaunchKernelGGL((gemm_bt<0, 1>), dim3(GLD / 128, N_TOT / 128), dim3(256), 0, stream,
                       x1b, BcT, bias384, gbuf, N_TOT, GLD, 256, GLD);
    // 4. hop softmax + aggregation
    hipLaunchKernelGGL(hop_z, dim3(N_HOPS), dim3(256), 0, stream,
                       x1b, gbuf, z);
    // 5. g_hop = z @ B2 + bias (split-K=8 partials, then reduce)
    hipLaunchKernelGGL(gemm_bt_sk, dim3(2, N_HOPS / 128, 8), dim3(256), 0, stream,
                       z, B2T, hopP, N_HOPS, 256, 256, 2048);
    hipLaunchKernelGGL(red_hop, dim3(N_HOPS * 64 / 256), dim3(256), 0, stream,
                       hopP, gat_b, gbuf);
    // 6. x1 = LN(g + x) -> bf16 (in place over x1b)
    hipLaunchKernelGGL(ln_add_bb, dim3(N_TOT / 4), dim3(256), 0, stream,
                       gbuf, x1b, ln1_g, ln1_b, x1b);
    // 7. fused FFN1+FFN2+LN2 -> out (fp32), hid stays on-chip
    hipLaunchKernelGGL(fused_ffn, dim3(N_TOT / 64), dim3(256), 0, stream,
                       x1b, W1T, b1, W2T, b2, ln2_g, ln2_b, out);
    (void)in_sizes; (void)n_in; (void)out_size; (void)ws_size;
}